// Round 1
// baseline (738.328 us; speedup 1.0000x reference)
//
#include <hip/hip_runtime.h>
#include <hip/hip_bf16.h>

#define DD 128
#define D3 (DD*DD*DD)      // 2097152
#define NB 8               // batch
#define NV 65536           // points
#define HID 256
#define LAT 128

// round-to-nearest-even f32 -> bf16, returned as the (exactly representable) f32 value
__device__ __forceinline__ float rbf(float x) {
    unsigned u = __float_as_uint(x);
    unsigned r = (u + 0x7fffu + ((u >> 16) & 1u)) & 0xFFFF0000u;
    return __uint_as_float(r);
}

// ---------------- SIREN MLP: h4 = bf16 MLP(x), stored as f32 [NB][HID] -------------
__global__ __launch_bounds__(1024) void k_mlp(
    const float* __restrict__ x,
    const float* __restrict__ w0, const float* __restrict__ b0,
    const float* __restrict__ w1, const float* __restrict__ b1,
    const float* __restrict__ w2, const float* __restrict__ b2,
    const float* __restrict__ w3, const float* __restrict__ b3,
    const float* __restrict__ w4, const float* __restrict__ b4,
    float* __restrict__ h4out)
{
    __shared__ float xs[NB][LAT];        // 4 KB
    __shared__ float hbuf[2][NB][HID];   // 16 KB
    __shared__ float part[4][NB][HID];   // 32 KB
    const int tid = threadIdx.x;
    const int j = tid & 255;
    const int kk = tid >> 8;             // 0..3 k-slice

    for (int i = tid; i < NB * LAT; i += 1024) xs[i >> 7][i & 127] = rbf(x[i]);
    __syncthreads();

    // ---- layer 0: [8,128]@[128,256], then sin(30*(m+b0)) ----
    {
        float acc[NB];
        #pragma unroll
        for (int b = 0; b < NB; ++b) acc[b] = 0.f;
        const int k0 = kk * 32;
        for (int k = k0; k < k0 + 32; ++k) {
            float wk = rbf(w0[k * HID + j]);
            #pragma unroll
            for (int b = 0; b < NB; ++b) acc[b] = fmaf(xs[b][k], wk, acc[b]);
        }
        #pragma unroll
        for (int b = 0; b < NB; ++b) part[kk][b][j] = acc[b];
    }
    __syncthreads();
    for (int i = tid; i < NB * HID; i += 1024) {
        int b = i >> 8, jj = i & 255;
        float s = (part[0][b][jj] + part[1][b][jj]) + (part[2][b][jj] + part[3][b][jj]);
        float m = rbf(s);                 // matmul output rounded to bf16
        m = rbf(m + rbf(b0[jj]));         // + bias (bf16 add)
        m = rbf(30.0f * m);               // * 30 (bf16 mul)
        hbuf[0][b][jj] = rbf(sinf(m));    // sin in f32, round bf16
    }
    __syncthreads();

    // ---- layers 1..3: h = sin(h + (h@w + b)); layer 4: h = h@w4 + b4 ----
    const float* ws_[4] = {w1, w2, w3, w4};
    const float* bs_[4] = {b1, b2, b3, b4};
    int cur = 0;
    for (int L = 0; L < 4; ++L) {
        const float* w = ws_[L];
        const float* bb = bs_[L];
        float acc[NB];
        #pragma unroll
        for (int b = 0; b < NB; ++b) acc[b] = 0.f;
        const int k0 = kk * 64;
        for (int k = k0; k < k0 + 64; ++k) {
            float wk = rbf(w[k * HID + j]);
            #pragma unroll
            for (int b = 0; b < NB; ++b) acc[b] = fmaf(hbuf[cur][b][k], wk, acc[b]);
        }
        __syncthreads();   // part[] from previous layer fully consumed already; safe to overwrite after barrier
        #pragma unroll
        for (int b = 0; b < NB; ++b) part[kk][b][j] = acc[b];
        __syncthreads();
        for (int i = tid; i < NB * HID; i += 1024) {
            int b = i >> 8, jj = i & 255;
            float s = (part[0][b][jj] + part[1][b][jj]) + (part[2][b][jj] + part[3][b][jj]);
            float t = rbf(s);
            t = rbf(t + rbf(bb[jj]));
            if (L < 3) {
                float u = rbf(hbuf[cur][b][jj] + t);
                hbuf[cur ^ 1][b][jj] = rbf(sinf(u));
            } else {
                h4out[b * HID + jj] = t;  // bf16 value stored as f32
            }
        }
        __syncthreads();
        cur ^= 1;
    }
}

// ------------- heads (f32) + trilinear splat (atomics into zeroed grid) -------------
__global__ __launch_bounds__(256) void k_heads_splat(
    const float* __restrict__ h4,
    const float* __restrict__ wc, const float* __restrict__ bc,
    const float* __restrict__ wv, const float* __restrict__ bv,
    const float* __restrict__ coords0, const float* __restrict__ values0,
    float* __restrict__ grid)
{
    __shared__ float hs[NB][HID];   // 8 KB
    const int tid = threadIdx.x;
    for (int i = tid; i < NB * HID; i += 256) hs[i >> 8][i & 255] = h4[i];
    __syncthreads();

    const int v = blockIdx.x * 256 + tid;

    float ac0[NB], ac1[NB], ac2[NB], av[NB];
    #pragma unroll
    for (int b = 0; b < NB; ++b) { ac0[b] = 0.f; ac1[b] = 0.f; ac2[b] = 0.f; av[b] = 0.f; }

    const float* wcp = wc + (size_t)3 * v;
    const float* wvp = wv + v;
    #pragma unroll 4
    for (int k = 0; k < HID; ++k) {
        float c0 = wcp[(size_t)k * (3 * NV) + 0];
        float c1 = wcp[(size_t)k * (3 * NV) + 1];
        float c2 = wcp[(size_t)k * (3 * NV) + 2];
        float vv = wvp[(size_t)k * NV];
        #pragma unroll
        for (int b = 0; b < NB; ++b) {
            float hb = hs[b][k];
            ac0[b] = fmaf(hb, c0, ac0[b]);
            ac1[b] = fmaf(hb, c1, ac1[b]);
            ac2[b] = fmaf(hb, c2, ac2[b]);
            av[b]  = fmaf(hb, vv, av[b]);
        }
    }

    const float bcx = bc[3 * v], bcy = bc[3 * v + 1], bcz = bc[3 * v + 2];
    const float bvv = bv[v], v0 = values0[v];
    const float cx = coords0[3 * v], cy = coords0[3 * v + 1], cz = coords0[3 * v + 2];
    const float factor = 0.5f * DD;

    #pragma unroll
    for (int b = 0; b < NB; ++b) {
        float px = factor * (cx + (ac0[b] + bcx)) + factor;
        float py = factor * (cy + (ac1[b] + bcy)) + factor;
        float pz = factor * (cz + (ac2[b] + bcz)) + factor;
        float val = fmaxf(v0 + (av[b] + bvv), 0.f);

        float fx = floorf(px), fy = floorf(py), fz = floorf(pz);
        int ix = (int)fx, iy = (int)fy, iz = (int)fz;
        float gx = px - fx, gy = py - fy, gz = pz - fz;
        float wx0 = 1.f - gx, wy0 = 1.f - gy, wz0 = 1.f - gz;

        float* g = grid + (size_t)b * D3;
        #pragma unroll
        for (int oz = 0; oz < 2; ++oz)
            #pragma unroll
            for (int oy = 0; oy < 2; ++oy)
                #pragma unroll
                for (int ox = 0; ox < 2; ++ox) {
                    float w = ((ox ? gx : wx0) * (oy ? gy : wy0)) * (oz ? gz : wz0);
                    long lin = ((long)(iz + oz) * DD + (iy + oy)) * DD + (ix + ox);
                    if (lin >= 0 && lin < (long)D3)
                        atomicAdd(g + lin, val * w);
                }
    }
}

// ------------------------- separable 7-tap gaussian blur ---------------------------
__global__ __launch_bounds__(256) void k_blur(const float* __restrict__ in,
                                              float* __restrict__ out, int shift)
{
    const long i = (long)blockIdx.x * 256 + threadIdx.x;
    const int p = (int)((i >> shift) & (DD - 1));

    // gaussian std=1, 7 taps, normalized (constant-folded; matches f32 ref within ~1 ulp)
    const double e1 = 0.6065306597126334, e2 = 0.1353352832366127, e3 = 0.011108996538242306;
    const double s = 1.0 + 2.0 * (e1 + e2 + e3);
    const float kw[7] = {(float)(e3 / s), (float)(e2 / s), (float)(e1 / s), (float)(1.0 / s),
                         (float)(e1 / s), (float)(e2 / s), (float)(e3 / s)};

    float acc = 0.f;
    #pragma unroll
    for (int j = -3; j <= 3; ++j) {
        int q = p + j;
        if (q >= 0 && q < DD)
            acc = fmaf(kw[j + 3], in[i + ((long)j << shift)], acc);
    }
    out[i] = acc;
}

extern "C" void kernel_launch(void* const* d_in, const int* in_sizes, int n_in,
                              void* d_out, int out_size, void* d_ws, size_t ws_size,
                              hipStream_t stream) {
    const float* x   = (const float*)d_in[0];
    const float* w0  = (const float*)d_in[1];
    const float* b0  = (const float*)d_in[2];
    const float* w1  = (const float*)d_in[3];
    const float* b1  = (const float*)d_in[4];
    const float* w2  = (const float*)d_in[5];
    const float* b2  = (const float*)d_in[6];
    const float* w3  = (const float*)d_in[7];
    const float* b3  = (const float*)d_in[8];
    const float* w4  = (const float*)d_in[9];
    const float* b4  = (const float*)d_in[10];
    const float* wc  = (const float*)d_in[11];
    const float* bc  = (const float*)d_in[12];
    const float* wv  = (const float*)d_in[13];
    const float* bv  = (const float*)d_in[14];
    const float* c0  = (const float*)d_in[15];
    const float* v0  = (const float*)d_in[16];

    float* out = (float*)d_out;
    float* gridbuf = (float*)d_ws;         // NB*D3 f32 = 64 MiB raw/intermediate grid
    float* h4 = out;                       // park h4 (2048 f32) at head of d_out;
                                           // consumed by splat before blur-z overwrites out

    // zero the splat target (harness does not re-poison between replays)
    hipMemsetAsync(gridbuf, 0, (size_t)NB * D3 * sizeof(float), stream);

    k_mlp<<<1, 1024, 0, stream>>>(x, w0, b0, w1, b1, w2, b2, w3, b3, w4, b4, h4);

    k_heads_splat<<<NV / 256, 256, 0, stream>>>(h4, wc, bc, wv, bv, c0, v0, gridbuf);

    const int nblk = (NB * D3) / 256;      // 65536
    k_blur<<<nblk, 256, 0, stream>>>(gridbuf, out, 14);  // z (stride 128*128)
    k_blur<<<nblk, 256, 0, stream>>>(out, gridbuf, 7);   // y (stride 128)
    k_blur<<<nblk, 256, 0, stream>>>(gridbuf, out, 0);   // x (stride 1)
}

// Round 2
// 724.659 us; speedup vs baseline: 1.0189x; 1.0189x over previous
//
#include <hip/hip_runtime.h>
#include <hip/hip_bf16.h>

#define DD 128
#define D3 (DD*DD*DD)      // 2097152
#define NB 8               // batch
#define NV 65536           // points
#define HID 256
#define LAT 128

// round-to-nearest-even f32 -> bf16, returned as the (exactly representable) f32 value
__device__ __forceinline__ float rbf(float x) {
    unsigned u = __float_as_uint(x);
    unsigned r = (u + 0x7fffu + ((u >> 16) & 1u)) & 0xFFFF0000u;
    return __uint_as_float(r);
}

// ---------------- SIREN MLP: h4 = bf16 MLP(x), stored as f32 [NB][HID] -------------
__global__ __launch_bounds__(1024) void k_mlp(
    const float* __restrict__ x,
    const float* __restrict__ w0, const float* __restrict__ b0,
    const float* __restrict__ w1, const float* __restrict__ b1,
    const float* __restrict__ w2, const float* __restrict__ b2,
    const float* __restrict__ w3, const float* __restrict__ b3,
    const float* __restrict__ w4, const float* __restrict__ b4,
    float* __restrict__ h4out)
{
    __shared__ float xs[NB][LAT];        // 4 KB
    __shared__ float hbuf[2][NB][HID];   // 16 KB
    __shared__ float part[4][NB][HID];   // 32 KB
    const int tid = threadIdx.x;
    const int j = tid & 255;
    const int kk = tid >> 8;             // 0..3 k-slice

    for (int i = tid; i < NB * LAT; i += 1024) xs[i >> 7][i & 127] = rbf(x[i]);
    __syncthreads();

    // ---- layer 0: [8,128]@[128,256], then sin(30*(m+b0)) ----
    {
        float acc[NB];
        #pragma unroll
        for (int b = 0; b < NB; ++b) acc[b] = 0.f;
        const int k0 = kk * 32;
        for (int k = k0; k < k0 + 32; ++k) {
            float wk = rbf(w0[k * HID + j]);
            #pragma unroll
            for (int b = 0; b < NB; ++b) acc[b] = fmaf(xs[b][k], wk, acc[b]);
        }
        #pragma unroll
        for (int b = 0; b < NB; ++b) part[kk][b][j] = acc[b];
    }
    __syncthreads();
    for (int i = tid; i < NB * HID; i += 1024) {
        int b = i >> 8, jj = i & 255;
        float s = (part[0][b][jj] + part[1][b][jj]) + (part[2][b][jj] + part[3][b][jj]);
        float m = rbf(s);                 // matmul output rounded to bf16
        m = rbf(m + rbf(b0[jj]));         // + bias (bf16 add)
        m = rbf(30.0f * m);               // * 30 (bf16 mul)
        hbuf[0][b][jj] = rbf(sinf(m));    // sin in f32, round bf16
    }
    __syncthreads();

    // ---- layers 1..3: h = sin(h + (h@w + b)); layer 4: h = h@w4 + b4 ----
    const float* ws_[4] = {w1, w2, w3, w4};
    const float* bs_[4] = {b1, b2, b3, b4};
    int cur = 0;
    for (int L = 0; L < 4; ++L) {
        const float* w = ws_[L];
        const float* bb = bs_[L];
        float acc[NB];
        #pragma unroll
        for (int b = 0; b < NB; ++b) acc[b] = 0.f;
        const int k0 = kk * 64;
        for (int k = k0; k < k0 + 64; ++k) {
            float wk = rbf(w[k * HID + j]);
            #pragma unroll
            for (int b = 0; b < NB; ++b) acc[b] = fmaf(hbuf[cur][b][k], wk, acc[b]);
        }
        __syncthreads();
        #pragma unroll
        for (int b = 0; b < NB; ++b) part[kk][b][j] = acc[b];
        __syncthreads();
        for (int i = tid; i < NB * HID; i += 1024) {
            int b = i >> 8, jj = i & 255;
            float s = (part[0][b][jj] + part[1][b][jj]) + (part[2][b][jj] + part[3][b][jj]);
            float t = rbf(s);
            t = rbf(t + rbf(bb[jj]));
            if (L < 3) {
                float u = rbf(hbuf[cur][b][jj] + t);
                hbuf[cur ^ 1][b][jj] = rbf(sinf(u));
            } else {
                h4out[b * HID + jj] = t;  // bf16 value stored as f32
            }
        }
        __syncthreads();
        cur ^= 1;
    }
}

// ------------- heads (f32) + trilinear splat, 8-way K-split per wave --------------
// tid = p*8 + s : p = point-in-block (0..31), s = k-slice (0..7, lane bits 0..2)
__global__ __launch_bounds__(256, 4) void k_heads_splat(
    const float* __restrict__ h4,
    const float* __restrict__ wc, const float* __restrict__ bc,
    const float* __restrict__ wv, const float* __restrict__ bv,
    const float* __restrict__ coords0, const float* __restrict__ values0,
    float* __restrict__ grid)
{
    // h transposed k-major with 16B skew per 32-k slice: addr(k,b) = k*8 + (k>>5)*4 + b
    // -> the 8 s-groups of a wave hit disjoint bank quads on ds_read_b128
    __shared__ float hsT[HID * NB + 32];   // 8.125 KB
    const int tid = threadIdx.x;
    for (int i = tid; i < NB * HID; i += 256) {
        int b = i >> 8, k = i & 255;
        hsT[k * 8 + (k >> 5) * 4 + b] = h4[b * HID + k];
    }
    __syncthreads();

    const int p = tid >> 3;          // 0..31
    const int s = tid & 7;           // k-slice 0..7
    const int v = blockIdx.x * 32 + p;

    float ac0[NB], ac1[NB], ac2[NB], av[NB];
    #pragma unroll
    for (int b = 0; b < NB; ++b) { ac0[b] = 0.f; ac1[b] = 0.f; ac2[b] = 0.f; av[b] = 0.f; }

    const float* pc = wc + (size_t)(s * 32) * (3 * NV) + 3 * v;
    const float* pv = wv + (size_t)(s * 32) * NV + v;
    const float* ph = hsT + (s * 32) * 8 + s * 4;   // addr(k=s*32, b=0)

    #pragma unroll 4
    for (int i = 0; i < 32; ++i) {
        float c0 = pc[0], c1 = pc[1], c2 = pc[2];
        float vv = pv[0];
        float4 h03 = *reinterpret_cast<const float4*>(ph);
        float4 h47 = *reinterpret_cast<const float4*>(ph + 4);
        ac0[0] = fmaf(h03.x, c0, ac0[0]); ac1[0] = fmaf(h03.x, c1, ac1[0]); ac2[0] = fmaf(h03.x, c2, ac2[0]); av[0] = fmaf(h03.x, vv, av[0]);
        ac0[1] = fmaf(h03.y, c0, ac0[1]); ac1[1] = fmaf(h03.y, c1, ac1[1]); ac2[1] = fmaf(h03.y, c2, ac2[1]); av[1] = fmaf(h03.y, vv, av[1]);
        ac0[2] = fmaf(h03.z, c0, ac0[2]); ac1[2] = fmaf(h03.z, c1, ac1[2]); ac2[2] = fmaf(h03.z, c2, ac2[2]); av[2] = fmaf(h03.z, vv, av[2]);
        ac0[3] = fmaf(h03.w, c0, ac0[3]); ac1[3] = fmaf(h03.w, c1, ac1[3]); ac2[3] = fmaf(h03.w, c2, ac2[3]); av[3] = fmaf(h03.w, vv, av[3]);
        ac0[4] = fmaf(h47.x, c0, ac0[4]); ac1[4] = fmaf(h47.x, c1, ac1[4]); ac2[4] = fmaf(h47.x, c2, ac2[4]); av[4] = fmaf(h47.x, vv, av[4]);
        ac0[5] = fmaf(h47.y, c0, ac0[5]); ac1[5] = fmaf(h47.y, c1, ac1[5]); ac2[5] = fmaf(h47.y, c2, ac2[5]); av[5] = fmaf(h47.y, vv, av[5]);
        ac0[6] = fmaf(h47.z, c0, ac0[6]); ac1[6] = fmaf(h47.z, c1, ac1[6]); ac2[6] = fmaf(h47.z, c2, ac2[6]); av[6] = fmaf(h47.z, vv, av[6]);
        ac0[7] = fmaf(h47.w, c0, ac0[7]); ac1[7] = fmaf(h47.w, c1, ac1[7]); ac2[7] = fmaf(h47.w, c2, ac2[7]); av[7] = fmaf(h47.w, vv, av[7]);
        pc += (size_t)3 * NV;
        pv += NV;
        ph += 8;
    }

    // butterfly reduce across the 3 slice bits (lane bits 0..2)
    #pragma unroll
    for (int m = 1; m <= 4; m <<= 1) {
        #pragma unroll
        for (int b = 0; b < NB; ++b) {
            ac0[b] += __shfl_xor(ac0[b], m);
            ac1[b] += __shfl_xor(ac1[b], m);
            ac2[b] += __shfl_xor(ac2[b], m);
            av[b]  += __shfl_xor(av[b], m);
        }
    }

    // lane (p,s) handles batch b = s; select statically to avoid scratch
    float A0 = 0.f, A1 = 0.f, A2 = 0.f, AV = 0.f;
    #pragma unroll
    for (int b = 0; b < NB; ++b)
        if (s == b) { A0 = ac0[b]; A1 = ac1[b]; A2 = ac2[b]; AV = av[b]; }

    const float bcx = bc[3 * v], bcy = bc[3 * v + 1], bcz = bc[3 * v + 2];
    const float bvv = bv[v], v0 = values0[v];
    const float cx = coords0[3 * v], cy = coords0[3 * v + 1], cz = coords0[3 * v + 2];
    const float factor = 0.5f * DD;

    float px = factor * (cx + (A0 + bcx)) + factor;
    float py = factor * (cy + (A1 + bcy)) + factor;
    float pz = factor * (cz + (A2 + bcz)) + factor;
    float val = fmaxf(v0 + (AV + bvv), 0.f);

    float fx = floorf(px), fy = floorf(py), fz = floorf(pz);
    int ix = (int)fx, iy = (int)fy, iz = (int)fz;
    float gx = px - fx, gy = py - fy, gz = pz - fz;
    float wx0 = 1.f - gx, wy0 = 1.f - gy, wz0 = 1.f - gz;

    float* g = grid + (size_t)s * D3;     // batch b == s
    #pragma unroll
    for (int oz = 0; oz < 2; ++oz)
        #pragma unroll
        for (int oy = 0; oy < 2; ++oy)
            #pragma unroll
            for (int ox = 0; ox < 2; ++ox) {
                float w = ((ox ? gx : wx0) * (oy ? gy : wy0)) * (oz ? gz : wz0);
                long lin = ((long)(iz + oz) * DD + (iy + oy)) * DD + (ix + ox);
                if (lin >= 0 && lin < (long)D3)
                    atomicAdd(g + lin, val * w);
            }
}

// ------------------------- separable 7-tap gaussian blur ---------------------------
__global__ __launch_bounds__(256) void k_blur(const float* __restrict__ in,
                                              float* __restrict__ out, int shift)
{
    const long i = (long)blockIdx.x * 256 + threadIdx.x;
    const int p = (int)((i >> shift) & (DD - 1));

    const double e1 = 0.6065306597126334, e2 = 0.1353352832366127, e3 = 0.011108996538242306;
    const double s = 1.0 + 2.0 * (e1 + e2 + e3);
    const float kw[7] = {(float)(e3 / s), (float)(e2 / s), (float)(e1 / s), (float)(1.0 / s),
                         (float)(e1 / s), (float)(e2 / s), (float)(e3 / s)};

    float acc = 0.f;
    #pragma unroll
    for (int j = -3; j <= 3; ++j) {
        int q = p + j;
        if (q >= 0 && q < DD)
            acc = fmaf(kw[j + 3], in[i + ((long)j << shift)], acc);
    }
    out[i] = acc;
}

extern "C" void kernel_launch(void* const* d_in, const int* in_sizes, int n_in,
                              void* d_out, int out_size, void* d_ws, size_t ws_size,
                              hipStream_t stream) {
    const float* x   = (const float*)d_in[0];
    const float* w0  = (const float*)d_in[1];
    const float* b0  = (const float*)d_in[2];
    const float* w1  = (const float*)d_in[3];
    const float* b1  = (const float*)d_in[4];
    const float* w2  = (const float*)d_in[5];
    const float* b2  = (const float*)d_in[6];
    const float* w3  = (const float*)d_in[7];
    const float* b3  = (const float*)d_in[8];
    const float* w4  = (const float*)d_in[9];
    const float* b4  = (const float*)d_in[10];
    const float* wc  = (const float*)d_in[11];
    const float* bc  = (const float*)d_in[12];
    const float* wv  = (const float*)d_in[13];
    const float* bv  = (const float*)d_in[14];
    const float* c0  = (const float*)d_in[15];
    const float* v0  = (const float*)d_in[16];

    float* out = (float*)d_out;
    float* gridbuf = (float*)d_ws;         // NB*D3 f32 = 64 MiB raw/intermediate grid
    float* h4 = out;                       // park h4 (2048 f32) at head of d_out;
                                           // consumed by splat before blur-z overwrites out

    hipMemsetAsync(gridbuf, 0, (size_t)NB * D3 * sizeof(float), stream);

    k_mlp<<<1, 1024, 0, stream>>>(x, w0, b0, w1, b1, w2, b2, w3, b3, w4, b4, h4);

    k_heads_splat<<<NV / 32, 256, 0, stream>>>(h4, wc, bc, wv, bv, c0, v0, gridbuf);

    const int nblk = (NB * D3) / 256;      // 65536
    k_blur<<<nblk, 256, 0, stream>>>(gridbuf, out, 14);  // z (stride 128*128)
    k_blur<<<nblk, 256, 0, stream>>>(out, gridbuf, 7);   // y (stride 128)
    k_blur<<<nblk, 256, 0, stream>>>(gridbuf, out, 0);   // x (stride 1)
}

// Round 3
// 589.388 us; speedup vs baseline: 1.2527x; 1.2295x over previous
//
#include <hip/hip_runtime.h>
#include <hip/hip_bf16.h>

#define DD 128
#define D3 (DD*DD*DD)      // 2097152
#define NB 8               // batch
#define NV 65536           // points
#define HID 256
#define LAT 128

// round-to-nearest-even f32 -> bf16, returned as the (exactly representable) f32 value
__device__ __forceinline__ float rbf(float x) {
    unsigned u = __float_as_uint(x);
    unsigned r = (u + 0x7fffu + ((u >> 16) & 1u)) & 0xFFFF0000u;
    return __uint_as_float(r);
}

// ---------------- SIREN MLP: h4 = bf16 MLP(x), stored as f32 [NB][HID] -------------
__global__ __launch_bounds__(1024) void k_mlp(
    const float* __restrict__ x,
    const float* __restrict__ w0, const float* __restrict__ b0,
    const float* __restrict__ w1, const float* __restrict__ b1,
    const float* __restrict__ w2, const float* __restrict__ b2,
    const float* __restrict__ w3, const float* __restrict__ b3,
    const float* __restrict__ w4, const float* __restrict__ b4,
    float* __restrict__ h4out)
{
    __shared__ float xs[NB][LAT];        // 4 KB
    __shared__ float hbuf[2][NB][HID];   // 16 KB
    __shared__ float part[4][NB][HID];   // 32 KB
    const int tid = threadIdx.x;
    const int j = tid & 255;
    const int kk = tid >> 8;             // 0..3 k-slice

    for (int i = tid; i < NB * LAT; i += 1024) xs[i >> 7][i & 127] = rbf(x[i]);
    __syncthreads();

    // ---- layer 0: [8,128]@[128,256], then sin(30*(m+b0)) ----
    {
        float acc[NB];
        #pragma unroll
        for (int b = 0; b < NB; ++b) acc[b] = 0.f;
        const int k0 = kk * 32;
        for (int k = k0; k < k0 + 32; ++k) {
            float wk = rbf(w0[k * HID + j]);
            #pragma unroll
            for (int b = 0; b < NB; ++b) acc[b] = fmaf(xs[b][k], wk, acc[b]);
        }
        #pragma unroll
        for (int b = 0; b < NB; ++b) part[kk][b][j] = acc[b];
    }
    __syncthreads();
    for (int i = tid; i < NB * HID; i += 1024) {
        int b = i >> 8, jj = i & 255;
        float s = (part[0][b][jj] + part[1][b][jj]) + (part[2][b][jj] + part[3][b][jj]);
        float m = rbf(s);                 // matmul output rounded to bf16
        m = rbf(m + rbf(b0[jj]));         // + bias (bf16 add)
        m = rbf(30.0f * m);               // * 30 (bf16 mul)
        hbuf[0][b][jj] = rbf(sinf(m));    // sin in f32, round bf16
    }
    __syncthreads();

    // ---- layers 1..3: h = sin(h + (h@w + b)); layer 4: h = h@w4 + b4 ----
    const float* ws_[4] = {w1, w2, w3, w4};
    const float* bs_[4] = {b1, b2, b3, b4};
    int cur = 0;
    for (int L = 0; L < 4; ++L) {
        const float* w = ws_[L];
        const float* bb = bs_[L];
        float acc[NB];
        #pragma unroll
        for (int b = 0; b < NB; ++b) acc[b] = 0.f;
        const int k0 = kk * 64;
        for (int k = k0; k < k0 + 64; ++k) {
            float wk = rbf(w[k * HID + j]);
            #pragma unroll
            for (int b = 0; b < NB; ++b) acc[b] = fmaf(hbuf[cur][b][k], wk, acc[b]);
        }
        __syncthreads();
        #pragma unroll
        for (int b = 0; b < NB; ++b) part[kk][b][j] = acc[b];
        __syncthreads();
        for (int i = tid; i < NB * HID; i += 1024) {
            int b = i >> 8, jj = i & 255;
            float s = (part[0][b][jj] + part[1][b][jj]) + (part[2][b][jj] + part[3][b][jj]);
            float t = rbf(s);
            t = rbf(t + rbf(bb[jj]));
            if (L < 3) {
                float u = rbf(hbuf[cur][b][jj] + t);
                hbuf[cur ^ 1][b][jj] = rbf(sinf(u));
            } else {
                h4out[b * HID + jj] = t;  // bf16 value stored as f32
            }
        }
        __syncthreads();
        cur ^= 1;
    }
}

// ----------------- heads: posval[b][v] = (px,py,pz,val), fully coalesced -----------
// block = 64 points x 4 k-slices (wave-uniform slice); tid = ks*64 + vl
#define PSTRIDE 36   // 32 channels + 4 pad floats (144 B, 16B-aligned, banks spread)
__global__ __launch_bounds__(256) void k_heads(
    const float* __restrict__ h4,
    const float* __restrict__ wc, const float* __restrict__ bc,
    const float* __restrict__ wv, const float* __restrict__ bv,
    const float* __restrict__ coords0, const float* __restrict__ values0,
    float4* __restrict__ posval)
{
    __shared__ float hsT[HID * NB];              // [k][b], 8 KB, broadcast reads
    __shared__ float part[4 * 64 * PSTRIDE];     // 36 KB
    const int tid = threadIdx.x;
    for (int i = tid; i < NB * HID; i += 256) {
        int b = i >> 8, k = i & 255;
        hsT[k * 8 + b] = h4[b * HID + k];
    }
    __syncthreads();

    const int vl = tid & 63;          // point-in-block, contiguous per wave
    const int ks = tid >> 6;          // k-slice 0..3 (wave-uniform)
    const int v  = blockIdx.x * 64 + vl;

    float ac0[NB], ac1[NB], ac2[NB], av[NB];
    #pragma unroll
    for (int b = 0; b < NB; ++b) { ac0[b] = 0.f; ac1[b] = 0.f; ac2[b] = 0.f; av[b] = 0.f; }

    const float* pc = wc + (size_t)(ks * 64) * (3 * NV) + 3 * v;
    const float* pv = wv + (size_t)(ks * 64) * NV + v;
    const float* ph = hsT + (ks * 64) * 8;

    #pragma unroll 4
    for (int i = 0; i < 64; ++i) {
        float c0 = pc[0], c1 = pc[1], c2 = pc[2];   // 12B-stride over lanes: contiguous 768B/wave
        float vv = pv[0];                            // contiguous 256B/wave
        float4 h03 = *reinterpret_cast<const float4*>(ph);      // LDS broadcast
        float4 h47 = *reinterpret_cast<const float4*>(ph + 4);
        ac0[0] = fmaf(h03.x, c0, ac0[0]); ac1[0] = fmaf(h03.x, c1, ac1[0]); ac2[0] = fmaf(h03.x, c2, ac2[0]); av[0] = fmaf(h03.x, vv, av[0]);
        ac0[1] = fmaf(h03.y, c0, ac0[1]); ac1[1] = fmaf(h03.y, c1, ac1[1]); ac2[1] = fmaf(h03.y, c2, ac2[1]); av[1] = fmaf(h03.y, vv, av[1]);
        ac0[2] = fmaf(h03.z, c0, ac0[2]); ac1[2] = fmaf(h03.z, c1, ac1[2]); ac2[2] = fmaf(h03.z, c2, ac2[2]); av[2] = fmaf(h03.z, vv, av[2]);
        ac0[3] = fmaf(h03.w, c0, ac0[3]); ac1[3] = fmaf(h03.w, c1, ac1[3]); ac2[3] = fmaf(h03.w, c2, ac2[3]); av[3] = fmaf(h03.w, vv, av[3]);
        ac0[4] = fmaf(h47.x, c0, ac0[4]); ac1[4] = fmaf(h47.x, c1, ac1[4]); ac2[4] = fmaf(h47.x, c2, ac2[4]); av[4] = fmaf(h47.x, vv, av[4]);
        ac0[5] = fmaf(h47.y, c0, ac0[5]); ac1[5] = fmaf(h47.y, c1, ac1[5]); ac2[5] = fmaf(h47.y, c2, ac2[5]); av[5] = fmaf(h47.y, vv, av[5]);
        ac0[6] = fmaf(h47.z, c0, ac0[6]); ac1[6] = fmaf(h47.z, c1, ac1[6]); ac2[6] = fmaf(h47.z, c2, ac2[6]); av[6] = fmaf(h47.z, vv, av[6]);
        ac0[7] = fmaf(h47.w, c0, ac0[7]); ac1[7] = fmaf(h47.w, c1, ac1[7]); ac2[7] = fmaf(h47.w, c2, ac2[7]); av[7] = fmaf(h47.w, vv, av[7]);
        pc += (size_t)3 * NV;
        pv += NV;
        ph += 8;
    }

    // stash per-slice partials: part[ks][vl][c], c = b*4 + {x,y,z,val}
    {
        float* pp = part + (ks * 64 + vl) * PSTRIDE;
        #pragma unroll
        for (int b = 0; b < NB; ++b) {
            float4 q = make_float4(ac0[b], ac1[b], ac2[b], av[b]);
            *reinterpret_cast<float4*>(pp + b * 4) = q;
        }
    }
    __syncthreads();

    // reduce: thread t -> v = t&63, batches {2*(t>>6), 2*(t>>6)+1}
    const int bp = tid >> 6;
    const float factor = 0.5f * DD;
    #pragma unroll
    for (int half = 0; half < 2; ++half) {
        const int b = bp * 2 + half;
        float4 A = make_float4(0.f, 0.f, 0.f, 0.f);
        #pragma unroll
        for (int k2 = 0; k2 < 4; ++k2) {
            float4 q = *reinterpret_cast<const float4*>(part + (k2 * 64 + vl) * PSTRIDE + b * 4);
            A.x += q.x; A.y += q.y; A.z += q.z; A.w += q.w;
        }
        float px = factor * (coords0[3 * v]     + (A.x + bc[3 * v]))     + factor;
        float py = factor * (coords0[3 * v + 1] + (A.y + bc[3 * v + 1])) + factor;
        float pz = factor * (coords0[3 * v + 2] + (A.z + bc[3 * v + 2])) + factor;
        float val = fmaxf(values0[v] + (A.w + bv[v]), 0.f);
        posval[(size_t)b * NV + v] = make_float4(px, py, pz, val);
    }
}

// ------------------- splat: one thread per (b,v), zero-skip, atomics ---------------
__global__ __launch_bounds__(256) void k_splat(const float4* __restrict__ posval,
                                               float* __restrict__ grid)
{
    const int idx = blockIdx.x * 256 + threadIdx.x;   // [b][v]
    const int b = idx >> 16;
    float4 q = posval[idx];
    if (q.w == 0.f) return;   // relu zeroed ~50% of points: no contribution

    float fx = floorf(q.x), fy = floorf(q.y), fz = floorf(q.z);
    int ix = (int)fx, iy = (int)fy, iz = (int)fz;
    float gx = q.x - fx, gy = q.y - fy, gz = q.z - fz;
    float wx0 = 1.f - gx, wy0 = 1.f - gy, wz0 = 1.f - gz;

    float* g = grid + (size_t)b * D3;
    #pragma unroll
    for (int oz = 0; oz < 2; ++oz)
        #pragma unroll
        for (int oy = 0; oy < 2; ++oy)
            #pragma unroll
            for (int ox = 0; ox < 2; ++ox) {
                float w = ((ox ? gx : wx0) * (oy ? gy : wy0)) * (oz ? gz : wz0);
                long lin = ((long)(iz + oz) * DD + (iy + oy)) * DD + (ix + ox);
                if (lin >= 0 && lin < (long)D3)
                    atomicAdd(g + lin, q.w * w);
            }
}

// ------------------------- separable 7-tap gaussian blur ---------------------------
__global__ __launch_bounds__(256) void k_blur(const float* __restrict__ in,
                                              float* __restrict__ out, int shift)
{
    const long i = (long)blockIdx.x * 256 + threadIdx.x;
    const int p = (int)((i >> shift) & (DD - 1));

    const double e1 = 0.6065306597126334, e2 = 0.1353352832366127, e3 = 0.011108996538242306;
    const double s = 1.0 + 2.0 * (e1 + e2 + e3);
    const float kw[7] = {(float)(e3 / s), (float)(e2 / s), (float)(e1 / s), (float)(1.0 / s),
                         (float)(e1 / s), (float)(e2 / s), (float)(e3 / s)};

    float acc = 0.f;
    #pragma unroll
    for (int j = -3; j <= 3; ++j) {
        int q = p + j;
        if (q >= 0 && q < DD)
            acc = fmaf(kw[j + 3], in[i + ((long)j << shift)], acc);
    }
    out[i] = acc;
}

extern "C" void kernel_launch(void* const* d_in, const int* in_sizes, int n_in,
                              void* d_out, int out_size, void* d_ws, size_t ws_size,
                              hipStream_t stream) {
    const float* x   = (const float*)d_in[0];
    const float* w0  = (const float*)d_in[1];
    const float* b0  = (const float*)d_in[2];
    const float* w1  = (const float*)d_in[3];
    const float* b1  = (const float*)d_in[4];
    const float* w2  = (const float*)d_in[5];
    const float* b2  = (const float*)d_in[6];
    const float* w3  = (const float*)d_in[7];
    const float* b3  = (const float*)d_in[8];
    const float* w4  = (const float*)d_in[9];
    const float* b4  = (const float*)d_in[10];
    const float* wc  = (const float*)d_in[11];
    const float* bc  = (const float*)d_in[12];
    const float* wv  = (const float*)d_in[13];
    const float* bv  = (const float*)d_in[14];
    const float* c0  = (const float*)d_in[15];
    const float* v0  = (const float*)d_in[16];

    float* out = (float*)d_out;
    float* gridbuf = (float*)d_ws;            // 64 MiB raw grid (atomic target)
    // stage small intermediates in d_out; all consumed before blur-z overwrites it
    float4* posval = (float4*)d_out;          // [NB][NV] float4 = 8 MiB
    float* h4 = out + 4 * 1024 * 1024;        // 2048 f32 at +16 MiB

    hipMemsetAsync(gridbuf, 0, (size_t)NB * D3 * sizeof(float), stream);

    k_mlp<<<1, 1024, 0, stream>>>(x, w0, b0, w1, b1, w2, b2, w3, b3, w4, b4, h4);

    k_heads<<<NV / 64, 256, 0, stream>>>(h4, wc, bc, wv, bv, c0, v0, posval);

    k_splat<<<(NB * NV) / 256, 256, 0, stream>>>(posval, gridbuf);

    const int nblk = (NB * D3) / 256;         // 65536
    k_blur<<<nblk, 256, 0, stream>>>(gridbuf, out, 14);  // z
    k_blur<<<nblk, 256, 0, stream>>>(out, gridbuf, 7);   // y
    k_blur<<<nblk, 256, 0, stream>>>(gridbuf, out, 0);   // x
}

// Round 4
// 469.670 us; speedup vs baseline: 1.5720x; 1.2549x over previous
//
#include <hip/hip_runtime.h>
#include <hip/hip_bf16.h>

#define DD 128
#define D3 (DD*DD*DD)      // 2097152
#define NB 8               // batch
#define NV 65536           // points
#define HID 256
#define LAT 128

// spatial bins: 32x16x8 voxels, indexed by (base+1) -> x:5, y:9, z:17 bins
#define BINX 5
#define BINY 9
#define BINZ 17
#define NBIN (BINX*BINY*BINZ)      // 765 per batch
#define NBIN_TOT (NBIN*NB)         // 6120

// round-to-nearest-even f32 -> bf16, returned as the (exactly representable) f32 value
__device__ __forceinline__ float rbf(float x) {
    unsigned u = __float_as_uint(x);
    unsigned r = (u + 0x7fffu + ((u >> 16) & 1u)) & 0xFFFF0000u;
    return __uint_as_float(r);
}

// ---------------- SIREN MLP: h4 = bf16 MLP(x), stored as f32 [NB][HID] -------------
__global__ __launch_bounds__(1024) void k_mlp(
    const float* __restrict__ x,
    const float* __restrict__ w0, const float* __restrict__ b0,
    const float* __restrict__ w1, const float* __restrict__ b1,
    const float* __restrict__ w2, const float* __restrict__ b2,
    const float* __restrict__ w3, const float* __restrict__ b3,
    const float* __restrict__ w4, const float* __restrict__ b4,
    float* __restrict__ h4out)
{
    __shared__ float xs[NB][LAT];        // 4 KB
    __shared__ float hbuf[2][NB][HID];   // 16 KB
    __shared__ float part[4][NB][HID];   // 32 KB
    const int tid = threadIdx.x;
    const int j = tid & 255;
    const int kk = tid >> 8;             // 0..3 k-slice

    for (int i = tid; i < NB * LAT; i += 1024) xs[i >> 7][i & 127] = rbf(x[i]);
    __syncthreads();

    // ---- layer 0: [8,128]@[128,256], then sin(30*(m+b0)) ----
    {
        float acc[NB];
        #pragma unroll
        for (int b = 0; b < NB; ++b) acc[b] = 0.f;
        const int k0 = kk * 32;
        for (int k = k0; k < k0 + 32; ++k) {
            float wk = rbf(w0[k * HID + j]);
            #pragma unroll
            for (int b = 0; b < NB; ++b) acc[b] = fmaf(xs[b][k], wk, acc[b]);
        }
        #pragma unroll
        for (int b = 0; b < NB; ++b) part[kk][b][j] = acc[b];
    }
    __syncthreads();
    for (int i = tid; i < NB * HID; i += 1024) {
        int b = i >> 8, jj = i & 255;
        float s = (part[0][b][jj] + part[1][b][jj]) + (part[2][b][jj] + part[3][b][jj]);
        float m = rbf(s);                 // matmul output rounded to bf16
        m = rbf(m + rbf(b0[jj]));         // + bias (bf16 add)
        m = rbf(30.0f * m);               // * 30 (bf16 mul)
        hbuf[0][b][jj] = rbf(sinf(m));    // sin in f32, round bf16
    }
    __syncthreads();

    // ---- layers 1..3: h = sin(h + (h@w + b)); layer 4: h = h@w4 + b4 ----
    const float* ws_[4] = {w1, w2, w3, w4};
    const float* bs_[4] = {b1, b2, b3, b4};
    int cur = 0;
    for (int L = 0; L < 4; ++L) {
        const float* w = ws_[L];
        const float* bb = bs_[L];
        float acc[NB];
        #pragma unroll
        for (int b = 0; b < NB; ++b) acc[b] = 0.f;
        const int k0 = kk * 64;
        for (int k = k0; k < k0 + 64; ++k) {
            float wk = rbf(w[k * HID + j]);
            #pragma unroll
            for (int b = 0; b < NB; ++b) acc[b] = fmaf(hbuf[cur][b][k], wk, acc[b]);
        }
        __syncthreads();
        #pragma unroll
        for (int b = 0; b < NB; ++b) part[kk][b][j] = acc[b];
        __syncthreads();
        for (int i = tid; i < NB * HID; i += 1024) {
            int b = i >> 8, jj = i & 255;
            float s = (part[0][b][jj] + part[1][b][jj]) + (part[2][b][jj] + part[3][b][jj]);
            float t = rbf(s);
            t = rbf(t + rbf(bb[jj]));
            if (L < 3) {
                float u = rbf(hbuf[cur][b][jj] + t);
                hbuf[cur ^ 1][b][jj] = rbf(sinf(u));
            } else {
                h4out[b * HID + jj] = t;  // bf16 value stored as f32
            }
        }
        __syncthreads();
        cur ^= 1;
    }
}

// ----------------- heads: posval[b][v] = (px,py,pz,val), fully coalesced -----------
// block = 64 points x 4 k-slices (wave-uniform slice); tid = ks*64 + vl
// two-phase cross-wave reduction (4 batches each) -> LDS 25.4 KB -> 6 blocks/CU
#define PSTRIDE 17   // 16 floats + 1 pad (stride 17 cycles all 32 banks, scalar rw)
__global__ __launch_bounds__(256) void k_heads(
    const float* __restrict__ h4,
    const float* __restrict__ wc, const float* __restrict__ bc,
    const float* __restrict__ wv, const float* __restrict__ bv,
    const float* __restrict__ coords0, const float* __restrict__ values0,
    float4* __restrict__ posval)
{
    __shared__ float hsT[HID * NB];              // [k][b], 8 KB, broadcast reads
    __shared__ float part[4 * 64 * PSTRIDE];     // 17.4 KB
    const int tid = threadIdx.x;
    for (int i = tid; i < NB * HID; i += 256) {
        int b = i >> 8, k = i & 255;
        hsT[k * 8 + b] = h4[b * HID + k];
    }
    __syncthreads();

    const int vl = tid & 63;          // point-in-block, contiguous per wave
    const int ks = tid >> 6;          // k-slice 0..3 (wave-uniform)
    const int v  = blockIdx.x * 64 + vl;

    float ac0[NB], ac1[NB], ac2[NB], av[NB];
    #pragma unroll
    for (int b = 0; b < NB; ++b) { ac0[b] = 0.f; ac1[b] = 0.f; ac2[b] = 0.f; av[b] = 0.f; }

    const float* pc = wc + (size_t)(ks * 64) * (3 * NV) + 3 * v;
    const float* pv = wv + (size_t)(ks * 64) * NV + v;
    const float* ph = hsT + (ks * 64) * 8;

    #pragma unroll 4
    for (int i = 0; i < 64; ++i) {
        float c0 = pc[0], c1 = pc[1], c2 = pc[2];   // contiguous 768B/wave
        float vv = pv[0];                            // contiguous 256B/wave
        float4 h03 = *reinterpret_cast<const float4*>(ph);      // LDS broadcast
        float4 h47 = *reinterpret_cast<const float4*>(ph + 4);
        ac0[0] = fmaf(h03.x, c0, ac0[0]); ac1[0] = fmaf(h03.x, c1, ac1[0]); ac2[0] = fmaf(h03.x, c2, ac2[0]); av[0] = fmaf(h03.x, vv, av[0]);
        ac0[1] = fmaf(h03.y, c0, ac0[1]); ac1[1] = fmaf(h03.y, c1, ac1[1]); ac2[1] = fmaf(h03.y, c2, ac2[1]); av[1] = fmaf(h03.y, vv, av[1]);
        ac0[2] = fmaf(h03.z, c0, ac0[2]); ac1[2] = fmaf(h03.z, c1, ac1[2]); ac2[2] = fmaf(h03.z, c2, ac2[2]); av[2] = fmaf(h03.z, vv, av[2]);
        ac0[3] = fmaf(h03.w, c0, ac0[3]); ac1[3] = fmaf(h03.w, c1, ac1[3]); ac2[3] = fmaf(h03.w, c2, ac2[3]); av[3] = fmaf(h03.w, vv, av[3]);
        ac0[4] = fmaf(h47.x, c0, ac0[4]); ac1[4] = fmaf(h47.x, c1, ac1[4]); ac2[4] = fmaf(h47.x, c2, ac2[4]); av[4] = fmaf(h47.x, vv, av[4]);
        ac0[5] = fmaf(h47.y, c0, ac0[5]); ac1[5] = fmaf(h47.y, c1, ac1[5]); ac2[5] = fmaf(h47.y, c2, ac2[5]); av[5] = fmaf(h47.y, vv, av[5]);
        ac0[6] = fmaf(h47.z, c0, ac0[6]); ac1[6] = fmaf(h47.z, c1, ac1[6]); ac2[6] = fmaf(h47.z, c2, ac2[6]); av[6] = fmaf(h47.z, vv, av[6]);
        ac0[7] = fmaf(h47.w, c0, ac0[7]); ac1[7] = fmaf(h47.w, c1, ac1[7]); ac2[7] = fmaf(h47.w, c2, ac2[7]); av[7] = fmaf(h47.w, vv, av[7]);
        pc += (size_t)3 * NV;
        pv += NV;
        ph += 8;
    }

    const float factor = 0.5f * DD;
    const int bp = tid >> 6;           // reduction: thread handles batch bp (+phase*4)
    float* pp = part + (ks * 64 + vl) * PSTRIDE;

    #pragma unroll
    for (int phase = 0; phase < 2; ++phase) {
        if (phase) __syncthreads();
        #pragma unroll
        for (int q = 0; q < 4; ++q) {
            int b = phase * 4 + q;
            pp[q * 4 + 0] = ac0[b]; pp[q * 4 + 1] = ac1[b];
            pp[q * 4 + 2] = ac2[b]; pp[q * 4 + 3] = av[b];
        }
        __syncthreads();
        {
            const int b = phase * 4 + bp;
            float A0 = 0.f, A1 = 0.f, A2 = 0.f, A3 = 0.f;
            #pragma unroll
            for (int k2 = 0; k2 < 4; ++k2) {
                const float* rp = part + (k2 * 64 + vl) * PSTRIDE + bp * 4;
                A0 += rp[0]; A1 += rp[1]; A2 += rp[2]; A3 += rp[3];
            }
            float px = factor * (coords0[3 * v]     + (A0 + bc[3 * v]))     + factor;
            float py = factor * (coords0[3 * v + 1] + (A1 + bc[3 * v + 1])) + factor;
            float pz = factor * (coords0[3 * v + 2] + (A2 + bc[3 * v + 2])) + factor;
            float val = fmaxf(values0[v] + (A3 + bv[v]), 0.f);
            posval[(size_t)b * NV + v] = make_float4(px, py, pz, val);
        }
    }
}

// ----------------------------- binning helpers -------------------------------------
__device__ __forceinline__ bool point_bin(float4 q, int& bin) {
    if (q.w == 0.f) return false;               // relu-zeroed: no contribution
    int ix = (int)floorf(q.x), iy = (int)floorf(q.y), iz = (int)floorf(q.z);
    if (ix < -1 || ix > 127 || iy < -1 || iy > 127 || iz < -1 || iz > 127) return false;
    bin = (((iz + 1) >> 3) * BINY + ((iy + 1) >> 4)) * BINX + ((ix + 1) >> 5);
    return true;
}

// --------------- k_count: LDS-aggregated histogram of points per bin ---------------
// 256 blocks x 256 threads; block handles 2048 consecutive points of one batch
__global__ __launch_bounds__(256) void k_count(const float4* __restrict__ posval,
                                               unsigned* __restrict__ binCount)
{
    __shared__ unsigned hist[NBIN];
    const int tid = threadIdx.x;
    const int batch = blockIdx.x >> 5;
    const size_t base = (size_t)batch * NV + (blockIdx.x & 31) * 2048;
    for (int i = tid; i < NBIN; i += 256) hist[i] = 0;
    __syncthreads();
    #pragma unroll
    for (int j = 0; j < 8; ++j) {
        float4 q = posval[base + j * 256 + tid];
        int bin;
        if (point_bin(q, bin)) atomicAdd(&hist[bin], 1u);
    }
    __syncthreads();
    for (int i = tid; i < NBIN; i += 256) {
        unsigned c = hist[i];
        if (c) atomicAdd(&binCount[batch * NBIN + i], c);
    }
}

// --------------- k_scan: exclusive scan over 6120 bins (single block) --------------
__global__ __launch_bounds__(1024) void k_scan(const unsigned* __restrict__ cnt,
                                               unsigned* __restrict__ start,
                                               unsigned* __restrict__ cursor)
{
    __shared__ unsigned partial[1024];
    const int t = threadIdx.x;
    const int base = t * 6;
    unsigned loc[6];
    unsigned s = 0;
    #pragma unroll
    for (int j = 0; j < 6; ++j) {
        int idx = base + j;
        unsigned c = (idx < NBIN_TOT) ? cnt[idx] : 0u;
        loc[j] = s;
        s += c;
    }
    partial[t] = s;
    __syncthreads();
    for (int off = 1; off < 1024; off <<= 1) {
        unsigned mine = partial[t];
        unsigned add = (t >= off) ? partial[t - off] : 0u;
        __syncthreads();
        partial[t] = mine + add;
        __syncthreads();
    }
    unsigned excl = (t > 0) ? partial[t - 1] : 0u;
    #pragma unroll
    for (int j = 0; j < 6; ++j) {
        int idx = base + j;
        if (idx < NBIN_TOT) {
            unsigned v = excl + loc[j];
            start[idx] = v;
            cursor[idx] = v;
        }
    }
    if (t == 1023) start[NBIN_TOT] = partial[1023];
}

// -------- k_scatter: write each point's float4 into its bin's contiguous range ------
__global__ __launch_bounds__(256) void k_scatter(const float4* __restrict__ posval,
                                                 unsigned* __restrict__ binCursor,
                                                 float4* __restrict__ sorted)
{
    __shared__ unsigned hist[NBIN];
    __shared__ unsigned bbase[NBIN];
    __shared__ unsigned lcur[NBIN];
    const int tid = threadIdx.x;
    const int batch = blockIdx.x >> 5;
    const size_t base = (size_t)batch * NV + (blockIdx.x & 31) * 2048;
    for (int i = tid; i < NBIN; i += 256) { hist[i] = 0; lcur[i] = 0; }
    __syncthreads();

    float4 q[8];
    int bn[8];
    #pragma unroll
    for (int j = 0; j < 8; ++j) {
        q[j] = posval[base + j * 256 + tid];
        bn[j] = -1;
        int bin;
        if (point_bin(q[j], bin)) { bn[j] = bin; atomicAdd(&hist[bin], 1u); }
    }
    __syncthreads();
    for (int i = tid; i < NBIN; i += 256) {
        unsigned c = hist[i];
        bbase[i] = c ? atomicAdd(&binCursor[batch * NBIN + i], c) : 0u;
    }
    __syncthreads();
    #pragma unroll
    for (int j = 0; j < 8; ++j) {
        if (bn[j] >= 0) {
            unsigned r = atomicAdd(&lcur[bn[j]], 1u);
            sorted[bbase[bn[j]] + r] = q[j];
        }
    }
}

// -------- k_binsplat: one block per 32x16x8 output brick; LDS accumulate -----------
// gathers from the <=8 bins overlapping the brick; writes brick with plain stores
__global__ __launch_bounds__(256) void k_binsplat(const float4* __restrict__ sorted,
                                                  const unsigned* __restrict__ binStart,
                                                  float* __restrict__ grid)
{
    __shared__ float brick[8 * 16 * 32];   // 16 KB
    const int tid = threadIdx.x;
    const int bid = blockIdx.x;            // [batch][obz 0..15][oby 0..7][obx 0..3]
    const int obx = bid & 3;
    const int oby = (bid >> 2) & 7;
    const int obz = (bid >> 5) & 15;
    const int batch = bid >> 9;

    for (int i = tid; i < 4096; i += 256) brick[i] = 0.f;
    __syncthreads();

    const int x0 = obx << 5, y0 = oby << 4, z0 = obz << 3;

    #pragma unroll
    for (int dz = 0; dz < 2; ++dz)
    #pragma unroll
    for (int dy = 0; dy < 2; ++dy)
    #pragma unroll
    for (int dx = 0; dx < 2; ++dx) {
        const int g = batch * NBIN + ((obz + dz) * BINY + (oby + dy)) * BINX + (obx + dx);
        const unsigned s = binStart[g], e = binStart[g + 1];
        for (unsigned i = s + tid; i < e; i += 256) {
            float4 q = sorted[i];
            float fx = floorf(q.x), fy = floorf(q.y), fz = floorf(q.z);
            int vx = (int)fx - x0, vy = (int)fy - y0, vz = (int)fz - z0;
            float gx = q.x - fx, gy = q.y - fy, gz = q.z - fz;
            float wx0 = 1.f - gx, wy0 = 1.f - gy, wz0 = 1.f - gz;
            #pragma unroll
            for (int oz = 0; oz < 2; ++oz)
            #pragma unroll
            for (int oy = 0; oy < 2; ++oy)
            #pragma unroll
            for (int ox = 0; ox < 2; ++ox) {
                int cx = vx + ox, cy = vy + oy, cz = vz + oz;
                if ((unsigned)cx < 32u && (unsigned)cy < 16u && (unsigned)cz < 8u) {
                    float w = ((ox ? gx : wx0) * (oy ? gy : wy0)) * (oz ? gz : wz0);
                    atomicAdd(&brick[(cz * 16 + cy) * 32 + cx], q.w * w);
                }
            }
        }
    }
    __syncthreads();

    // write brick: 1024 float4s, coalesced 128B rows
    #pragma unroll
    for (int jj = 0; jj < 4; ++jj) {
        int fj = jj * 256 + tid;
        int vx4 = fj & 7;
        int vy = (fj >> 3) & 15;
        int vz = fj >> 7;
        float4 val = *reinterpret_cast<const float4*>(&brick[(vz * 16 + vy) * 32 + vx4 * 4]);
        size_t o = (size_t)batch * D3 + (size_t)(z0 + vz) * (DD * DD) + (size_t)(y0 + vy) * DD + x0 + vx4 * 4;
        *reinterpret_cast<float4*>(grid + o) = val;
    }
}

// ------------------------- separable 7-tap gaussian blur (pencil) ------------------
__global__ __launch_bounds__(256) void k_blur(const float* __restrict__ in,
                                              float* __restrict__ out, int shift)
{
    const long i = (long)blockIdx.x * 256 + threadIdx.x;
    const int p = (int)((i >> shift) & (DD - 1));

    const double e1 = 0.6065306597126334, e2 = 0.1353352832366127, e3 = 0.011108996538242306;
    const double s = 1.0 + 2.0 * (e1 + e2 + e3);
    const float kw[7] = {(float)(e3 / s), (float)(e2 / s), (float)(e1 / s), (float)(1.0 / s),
                         (float)(e1 / s), (float)(e2 / s), (float)(e3 / s)};

    float acc = 0.f;
    #pragma unroll
    for (int j = -3; j <= 3; ++j) {
        int q = p + j;
        if (q >= 0 && q < DD)
            acc = fmaf(kw[j + 3], in[i + ((long)j << shift)], acc);
    }
    out[i] = acc;
}

// ------------------ fused y+x blur: 32-row y-strips per (batch, z) -----------------
__global__ __launch_bounds__(256) void k_blur_yx(const float* __restrict__ in,
                                                 float* __restrict__ out)
{
    __shared__ float sin_[38 * 128];   // 19 KB: 32 rows + 3 halo each side
    __shared__ float sy[32 * 128];     // 16 KB: y-blur result

    const double e1 = 0.6065306597126334, e2 = 0.1353352832366127, e3 = 0.011108996538242306;
    const double ss = 1.0 + 2.0 * (e1 + e2 + e3);
    const float kw[7] = {(float)(e3 / ss), (float)(e2 / ss), (float)(e1 / ss), (float)(1.0 / ss),
                         (float)(e1 / ss), (float)(e2 / ss), (float)(e3 / ss)};

    const int tid = threadIdx.x;
    const int bid = blockIdx.x;            // [batch][z][ytile]
    const int ytile = bid & 3;
    const int z = (bid >> 2) & 127;
    const int batch = bid >> 9;
    const int y0 = ytile << 5;
    const size_t slab = (size_t)batch * D3 + (size_t)z * (DD * DD);

    for (int i = tid; i < 38 * 128; i += 256) {
        int row = i >> 7, xx = i & 127;
        int gy = y0 + row - 3;
        sin_[i] = (gy >= 0 && gy < DD) ? in[slab + (size_t)gy * DD + xx] : 0.f;
    }
    __syncthreads();

    for (int i = tid; i < 32 * 128; i += 256) {
        int r = i >> 7, xx = i & 127;
        float acc = 0.f;
        #pragma unroll
        for (int j = 0; j < 7; ++j)
            acc = fmaf(kw[j], sin_[(r + j) * 128 + xx], acc);
        sy[i] = acc;
    }
    __syncthreads();

    for (int i = tid; i < 32 * 128; i += 256) {
        int r = i >> 7, xx = i & 127;
        float acc = 0.f;
        #pragma unroll
        for (int j = -3; j <= 3; ++j) {
            int qx = xx + j;
            if (qx >= 0 && qx < DD)
                acc = fmaf(kw[j + 3], sy[r * 128 + qx], acc);
        }
        out[slab + (size_t)(y0 + r) * DD + xx] = acc;
    }
}

extern "C" void kernel_launch(void* const* d_in, const int* in_sizes, int n_in,
                              void* d_out, int out_size, void* d_ws, size_t ws_size,
                              hipStream_t stream) {
    const float* x   = (const float*)d_in[0];
    const float* w0  = (const float*)d_in[1];
    const float* b0  = (const float*)d_in[2];
    const float* w1  = (const float*)d_in[3];
    const float* b1  = (const float*)d_in[4];
    const float* w2  = (const float*)d_in[5];
    const float* b2  = (const float*)d_in[6];
    const float* w3  = (const float*)d_in[7];
    const float* b3  = (const float*)d_in[8];
    const float* w4  = (const float*)d_in[9];
    const float* b4  = (const float*)d_in[10];
    const float* wc  = (const float*)d_in[11];
    const float* bc  = (const float*)d_in[12];
    const float* wv  = (const float*)d_in[13];
    const float* bv  = (const float*)d_in[14];
    const float* c0  = (const float*)d_in[15];
    const float* v0  = (const float*)d_in[16];

    float* out = (float*)d_out;
    // d_out staging (all consumed before k_binsplat rewrites d_out as the raw grid):
    float4* posval = (float4*)d_out;                  // [NB][NV] float4 = 8 MiB
    float* h4 = out + 4 * 1024 * 1024;                // 2048 f32 at +16 MiB
    // ws staging (all consumed before blur-z rewrites ws):
    float4* sorted = (float4*)d_ws;                   // 8 MiB
    unsigned* binCount  = (unsigned*)((char*)d_ws + (8u << 20));
    unsigned* binStart  = binCount + 8192;
    unsigned* binCursor = binStart + 8192;

    hipMemsetAsync(binCount, 0, NBIN_TOT * sizeof(unsigned), stream);

    k_mlp<<<1, 1024, 0, stream>>>(x, w0, b0, w1, b1, w2, b2, w3, b3, w4, b4, h4);

    k_heads<<<NV / 64, 256, 0, stream>>>(h4, wc, bc, wv, bv, c0, v0, posval);

    k_count<<<256, 256, 0, stream>>>(posval, binCount);
    k_scan<<<1, 1024, 0, stream>>>(binCount, binStart, binCursor);
    k_scatter<<<256, 256, 0, stream>>>(posval, binCursor, sorted);
    k_binsplat<<<NB * 512, 256, 0, stream>>>(sorted, binStart, out);   // raw grid -> d_out

    const int nblk = (NB * D3) / 256;   // 65536
    k_blur<<<nblk, 256, 0, stream>>>(out, (float*)d_ws, 14);           // z: d_out -> ws
    k_blur_yx<<<NB * 512, 256, 0, stream>>>((float*)d_ws, out);        // y+x: ws -> d_out
}

// Round 5
// 407.192 us; speedup vs baseline: 1.8132x; 1.1534x over previous
//
#include <hip/hip_runtime.h>
#include <hip/hip_bf16.h>

#define DD 128
#define D3 (DD*DD*DD)      // 2097152
#define NB 8               // batch
#define NV 65536           // points
#define HID 256
#define LAT 128

// bricks: 32x8x4 voxels -> 4 x 16 x 32 = 2048 per batch, 16384 total
#define NBIN 2048
#define NBIN_TOT (NBIN*NB) // 16384

// round-to-nearest-even f32 -> bf16, returned as the (exactly representable) f32 value
__device__ __forceinline__ float rbf(float x) {
    unsigned u = __float_as_uint(x);
    unsigned r = (u + 0x7fffu + ((u >> 16) & 1u)) & 0xFFFF0000u;
    return __uint_as_float(r);
}

// ---------------- SIREN MLP: h4 = bf16 MLP(x), stored as f32 [NB][HID] -------------
__global__ __launch_bounds__(1024) void k_mlp(
    const float* __restrict__ x,
    const float* __restrict__ w0, const float* __restrict__ b0,
    const float* __restrict__ w1, const float* __restrict__ b1,
    const float* __restrict__ w2, const float* __restrict__ b2,
    const float* __restrict__ w3, const float* __restrict__ b3,
    const float* __restrict__ w4, const float* __restrict__ b4,
    float* __restrict__ h4out)
{
    __shared__ float xs[NB][LAT];        // 4 KB
    __shared__ float hbuf[2][NB][HID];   // 16 KB
    __shared__ float part[4][NB][HID];   // 32 KB
    const int tid = threadIdx.x;
    const int j = tid & 255;
    const int kk = tid >> 8;             // 0..3 k-slice

    for (int i = tid; i < NB * LAT; i += 1024) xs[i >> 7][i & 127] = rbf(x[i]);
    __syncthreads();

    // ---- layer 0: [8,128]@[128,256], then sin(30*(m+b0)) ----
    {
        float acc[NB];
        #pragma unroll
        for (int b = 0; b < NB; ++b) acc[b] = 0.f;
        const int k0 = kk * 32;
        for (int k = k0; k < k0 + 32; ++k) {
            float wk = rbf(w0[k * HID + j]);
            #pragma unroll
            for (int b = 0; b < NB; ++b) acc[b] = fmaf(xs[b][k], wk, acc[b]);
        }
        #pragma unroll
        for (int b = 0; b < NB; ++b) part[kk][b][j] = acc[b];
    }
    __syncthreads();
    for (int i = tid; i < NB * HID; i += 1024) {
        int b = i >> 8, jj = i & 255;
        float s = (part[0][b][jj] + part[1][b][jj]) + (part[2][b][jj] + part[3][b][jj]);
        float m = rbf(s);                 // matmul output rounded to bf16
        m = rbf(m + rbf(b0[jj]));         // + bias (bf16 add)
        m = rbf(30.0f * m);               // * 30 (bf16 mul)
        hbuf[0][b][jj] = rbf(sinf(m));    // sin in f32, round bf16
    }
    __syncthreads();

    // ---- layers 1..3: h = sin(h + (h@w + b)); layer 4: h = h@w4 + b4 ----
    const float* ws_[4] = {w1, w2, w3, w4};
    const float* bs_[4] = {b1, b2, b3, b4};
    int cur = 0;
    for (int L = 0; L < 4; ++L) {
        const float* w = ws_[L];
        const float* bb = bs_[L];
        float acc[NB];
        #pragma unroll
        for (int b = 0; b < NB; ++b) acc[b] = 0.f;
        const int k0 = kk * 64;
        for (int k = k0; k < k0 + 64; ++k) {
            float wk = rbf(w[k * HID + j]);
            #pragma unroll
            for (int b = 0; b < NB; ++b) acc[b] = fmaf(hbuf[cur][b][k], wk, acc[b]);
        }
        __syncthreads();
        #pragma unroll
        for (int b = 0; b < NB; ++b) part[kk][b][j] = acc[b];
        __syncthreads();
        for (int i = tid; i < NB * HID; i += 1024) {
            int b = i >> 8, jj = i & 255;
            float s = (part[0][b][jj] + part[1][b][jj]) + (part[2][b][jj] + part[3][b][jj]);
            float t = rbf(s);
            t = rbf(t + rbf(bb[jj]));
            if (L < 3) {
                float u = rbf(hbuf[cur][b][jj] + t);
                hbuf[cur ^ 1][b][jj] = rbf(sinf(u));
            } else {
                h4out[b * HID + jj] = t;  // bf16 value stored as f32
            }
        }
        __syncthreads();
        cur ^= 1;
    }
}

// ----------------- heads: posval[b][v] = (px,py,pz,val), fully coalesced -----------
// block = 64 points x 4 k-slices (wave-uniform slice); tid = ks*64 + vl
#define PSTRIDE 17
__global__ __launch_bounds__(256) void k_heads(
    const float* __restrict__ h4,
    const float* __restrict__ wc, const float* __restrict__ bc,
    const float* __restrict__ wv, const float* __restrict__ bv,
    const float* __restrict__ coords0, const float* __restrict__ values0,
    float4* __restrict__ posval)
{
    __shared__ float hsT[HID * NB];              // [k][b], 8 KB, broadcast reads
    __shared__ float part[4 * 64 * PSTRIDE];     // 17.4 KB
    const int tid = threadIdx.x;
    for (int i = tid; i < NB * HID; i += 256) {
        int b = i >> 8, k = i & 255;
        hsT[k * 8 + b] = h4[b * HID + k];
    }
    __syncthreads();

    const int vl = tid & 63;          // point-in-block, contiguous per wave
    const int ks = tid >> 6;          // k-slice 0..3 (wave-uniform)
    const int v  = blockIdx.x * 64 + vl;

    float ac0[NB], ac1[NB], ac2[NB], av[NB];
    #pragma unroll
    for (int b = 0; b < NB; ++b) { ac0[b] = 0.f; ac1[b] = 0.f; ac2[b] = 0.f; av[b] = 0.f; }

    const float* pc = wc + (size_t)(ks * 64) * (3 * NV) + 3 * v;
    const float* pv = wv + (size_t)(ks * 64) * NV + v;
    const float* ph = hsT + (ks * 64) * 8;

    #pragma unroll 4
    for (int i = 0; i < 64; ++i) {
        float c0 = pc[0], c1 = pc[1], c2 = pc[2];   // contiguous 768B/wave
        float vv = pv[0];                            // contiguous 256B/wave
        float4 h03 = *reinterpret_cast<const float4*>(ph);      // LDS broadcast
        float4 h47 = *reinterpret_cast<const float4*>(ph + 4);
        ac0[0] = fmaf(h03.x, c0, ac0[0]); ac1[0] = fmaf(h03.x, c1, ac1[0]); ac2[0] = fmaf(h03.x, c2, ac2[0]); av[0] = fmaf(h03.x, vv, av[0]);
        ac0[1] = fmaf(h03.y, c0, ac0[1]); ac1[1] = fmaf(h03.y, c1, ac1[1]); ac2[1] = fmaf(h03.y, c2, ac2[1]); av[1] = fmaf(h03.y, vv, av[1]);
        ac0[2] = fmaf(h03.z, c0, ac0[2]); ac1[2] = fmaf(h03.z, c1, ac1[2]); ac2[2] = fmaf(h03.z, c2, ac2[2]); av[2] = fmaf(h03.z, vv, av[2]);
        ac0[3] = fmaf(h03.w, c0, ac0[3]); ac1[3] = fmaf(h03.w, c1, ac1[3]); ac2[3] = fmaf(h03.w, c2, ac2[3]); av[3] = fmaf(h03.w, vv, av[3]);
        ac0[4] = fmaf(h47.x, c0, ac0[4]); ac1[4] = fmaf(h47.x, c1, ac1[4]); ac2[4] = fmaf(h47.x, c2, ac2[4]); av[4] = fmaf(h47.x, vv, av[4]);
        ac0[5] = fmaf(h47.y, c0, ac0[5]); ac1[5] = fmaf(h47.y, c1, ac1[5]); ac2[5] = fmaf(h47.y, c2, ac2[5]); av[5] = fmaf(h47.y, vv, av[5]);
        ac0[6] = fmaf(h47.z, c0, ac0[6]); ac1[6] = fmaf(h47.z, c1, ac1[6]); ac2[6] = fmaf(h47.z, c2, ac2[6]); av[6] = fmaf(h47.z, vv, av[6]);
        ac0[7] = fmaf(h47.w, c0, ac0[7]); ac1[7] = fmaf(h47.w, c1, ac1[7]); ac2[7] = fmaf(h47.w, c2, ac2[7]); av[7] = fmaf(h47.w, vv, av[7]);
        pc += (size_t)3 * NV;
        pv += NV;
        ph += 8;
    }

    const float factor = 0.5f * DD;
    const int bp = tid >> 6;           // reduction: thread handles batch bp (+phase*4)
    float* pp = part + (ks * 64 + vl) * PSTRIDE;

    #pragma unroll
    for (int phase = 0; phase < 2; ++phase) {
        if (phase) __syncthreads();
        #pragma unroll
        for (int q = 0; q < 4; ++q) {
            int b = phase * 4 + q;
            pp[q * 4 + 0] = ac0[b]; pp[q * 4 + 1] = ac1[b];
            pp[q * 4 + 2] = ac2[b]; pp[q * 4 + 3] = av[b];
        }
        __syncthreads();
        {
            const int b = phase * 4 + bp;
            float A0 = 0.f, A1 = 0.f, A2 = 0.f, A3 = 0.f;
            #pragma unroll
            for (int k2 = 0; k2 < 4; ++k2) {
                const float* rp = part + (k2 * 64 + vl) * PSTRIDE + bp * 4;
                A0 += rp[0]; A1 += rp[1]; A2 += rp[2]; A3 += rp[3];
            }
            float px = factor * (coords0[3 * v]     + (A0 + bc[3 * v]))     + factor;
            float py = factor * (coords0[3 * v + 1] + (A1 + bc[3 * v + 1])) + factor;
            float pz = factor * (coords0[3 * v + 2] + (A2 + bc[3 * v + 2])) + factor;
            float val = fmaxf(values0[v] + (A3 + bv[v]), 0.f);
            posval[(size_t)b * NV + v] = make_float4(px, py, pz, val);
        }
    }
}

// ----------------------------- binning helpers -------------------------------------
// brick(bx,by,bz) covers voxels x:[bx*32,+32) y:[by*8,+8) z:[bz*4,+4); bin=(bz*16+by)*4+bx
__device__ __forceinline__ bool point_base(float4 q, int& ix, int& iy, int& iz) {
    if (q.w == 0.f) return false;                   // relu-zeroed: no contribution
    ix = (int)floorf(q.x); iy = (int)floorf(q.y); iz = (int)floorf(q.z);
    return ix >= -1 && ix <= 127 && iy >= -1 && iy <= 127 && iz >= -1 && iz <= 127;
}

__device__ __forceinline__ void brick_span(int ix, int iy, int iz,
                                           int& bx0, int& bx1, int& by0, int& by1,
                                           int& bz0, int& bz1) {
    bx0 = (ix < 0 ? 0 : ix) >> 5;  bx1 = (ix + 1 > 127 ? 127 : ix + 1) >> 5;
    by0 = (iy < 0 ? 0 : iy) >> 3;  by1 = (iy + 1 > 127 ? 127 : iy + 1) >> 3;
    bz0 = (iz < 0 ? 0 : iz) >> 2;  bz1 = (iz + 1 > 127 ? 127 : iz + 1) >> 2;
}

// --------------- k_count: LDS histogram of (duplicated) entries per brick ----------
// 256 blocks; block handles 2048 consecutive points of one batch
__global__ __launch_bounds__(256) void k_count(const float4* __restrict__ posval,
                                               unsigned* __restrict__ binCount)
{
    __shared__ unsigned hist[NBIN];   // 8 KB
    const int tid = threadIdx.x;
    const int batch = blockIdx.x >> 5;
    const size_t base = (size_t)batch * NV + (blockIdx.x & 31) * 2048;
    for (int i = tid; i < NBIN; i += 256) hist[i] = 0;
    __syncthreads();
    #pragma unroll
    for (int j = 0; j < 8; ++j) {
        float4 q = posval[base + j * 256 + tid];
        int ix, iy, iz;
        if (point_base(q, ix, iy, iz)) {
            int bx0, bx1, by0, by1, bz0, bz1;
            brick_span(ix, iy, iz, bx0, bx1, by0, by1, bz0, bz1);
            for (int bz = bz0; bz <= bz1; ++bz)
                for (int by = by0; by <= by1; ++by)
                    for (int bx = bx0; bx <= bx1; ++bx)
                        atomicAdd(&hist[(bz * 16 + by) * 4 + bx], 1u);
        }
    }
    __syncthreads();
    for (int i = tid; i < NBIN; i += 256) {
        unsigned c = hist[i];
        if (c) atomicAdd(&binCount[batch * NBIN + i], c);
    }
}

// --------------- k_scan: exclusive scan over 16384 bins (single block) -------------
__global__ __launch_bounds__(1024) void k_scan(const unsigned* __restrict__ cnt,
                                               unsigned* __restrict__ start,
                                               unsigned* __restrict__ cursor)
{
    __shared__ unsigned partial[1024];
    const int t = threadIdx.x;
    const int base = t * 16;
    unsigned s = 0;
    #pragma unroll
    for (int j = 0; j < 16; ++j) s += cnt[base + j];
    partial[t] = s;
    __syncthreads();
    for (int off = 1; off < 1024; off <<= 1) {
        unsigned mine = partial[t];
        unsigned add = (t >= off) ? partial[t - off] : 0u;
        __syncthreads();
        partial[t] = mine + add;
        __syncthreads();
    }
    unsigned run = (t > 0) ? partial[t - 1] : 0u;
    #pragma unroll
    for (int j = 0; j < 16; ++j) {
        start[base + j] = run;
        cursor[base + j] = run;
        run += cnt[base + j];
    }
    if (t == 1023) start[NBIN_TOT] = partial[1023];
}

// -------- k_scatter: copy each point into every touched brick's contiguous range ----
__global__ __launch_bounds__(256) void k_scatter(const float4* __restrict__ posval,
                                                 unsigned* __restrict__ binCursor,
                                                 float4* __restrict__ sorted)
{
    __shared__ unsigned hist[NBIN];    // counts, then reused as local cursor
    __shared__ unsigned bbase[NBIN];
    const int tid = threadIdx.x;
    const int batch = blockIdx.x >> 5;
    const size_t base = (size_t)batch * NV + (blockIdx.x & 31) * 2048;
    for (int i = tid; i < NBIN; i += 256) hist[i] = 0;
    __syncthreads();

    float4 q[8];
    #pragma unroll
    for (int j = 0; j < 8; ++j) {
        q[j] = posval[base + j * 256 + tid];
        int ix, iy, iz;
        if (point_base(q[j], ix, iy, iz)) {
            int bx0, bx1, by0, by1, bz0, bz1;
            brick_span(ix, iy, iz, bx0, bx1, by0, by1, bz0, bz1);
            for (int bz = bz0; bz <= bz1; ++bz)
                for (int by = by0; by <= by1; ++by)
                    for (int bx = bx0; bx <= bx1; ++bx)
                        atomicAdd(&hist[(bz * 16 + by) * 4 + bx], 1u);
        }
    }
    __syncthreads();
    for (int i = tid; i < NBIN; i += 256) {
        unsigned c = hist[i];
        bbase[i] = c ? atomicAdd(&binCursor[batch * NBIN + i], c) : 0u;
    }
    __syncthreads();
    for (int i = tid; i < NBIN; i += 256) hist[i] = 0;   // reuse as local cursor
    __syncthreads();
    #pragma unroll
    for (int j = 0; j < 8; ++j) {
        int ix, iy, iz;
        if (point_base(q[j], ix, iy, iz)) {
            int bx0, bx1, by0, by1, bz0, bz1;
            brick_span(ix, iy, iz, bx0, bx1, by0, by1, bz0, bz1);
            for (int bz = bz0; bz <= bz1; ++bz)
                for (int by = by0; by <= by1; ++by)
                    for (int bx = bx0; bx <= bx1; ++bx) {
                        int bin = (bz * 16 + by) * 4 + bx;
                        unsigned r = atomicAdd(&hist[bin], 1u);
                        sorted[bbase[bin] + r] = q[j];
                    }
        }
    }
}

// -------- k_binsplat: one block per 32x8x4 brick; exact list; LDS accumulate -------
__global__ __launch_bounds__(256) void k_binsplat(const float4* __restrict__ sorted,
                                                  const unsigned* __restrict__ binStart,
                                                  float* __restrict__ grid)
{
    __shared__ float brick[4 * 8 * 32];   // 4 KB
    const int tid = threadIdx.x;
    const int bid = blockIdx.x;           // [batch][bz 0..31][by 0..15][bx 0..3]
    const int bx = bid & 3;
    const int by = (bid >> 2) & 15;
    const int bz = (bid >> 6) & 31;
    const int batch = bid >> 11;
    const int x0 = bx << 5, y0 = by << 3, z0 = bz << 2;

    const unsigned s = binStart[bid], e = binStart[bid + 1];

    // output address for this thread's float4 (one per thread, 128B rows)
    const int vx4 = tid & 7, cy = (tid >> 3) & 7, cz = tid >> 6;
    const size_t o = (size_t)batch * D3 + (size_t)(z0 + cz) * (DD * DD)
                   + (size_t)(y0 + cy) * DD + x0 + vx4 * 4;

    if (s == e) {   // empty brick: pure zero-write (replaces global memset)
        *reinterpret_cast<float4*>(grid + o) = make_float4(0.f, 0.f, 0.f, 0.f);
        return;
    }

    for (int i = tid; i < 1024; i += 256) brick[i] = 0.f;
    __syncthreads();

    for (unsigned i = s + tid; i < e; i += 256) {
        float4 q = sorted[i];
        float fx = floorf(q.x), fy = floorf(q.y), fz = floorf(q.z);
        int vx = (int)fx - x0, vy = (int)fy - y0, vz = (int)fz - z0;
        float gx = q.x - fx, gy = q.y - fy, gz = q.z - fz;
        float wx0 = 1.f - gx, wy0 = 1.f - gy, wz0 = 1.f - gz;
        #pragma unroll
        for (int oz = 0; oz < 2; ++oz)
        #pragma unroll
        for (int oy = 0; oy < 2; ++oy)
        #pragma unroll
        for (int ox = 0; ox < 2; ++ox) {
            int cxx = vx + ox, cyy = vy + oy, czz = vz + oz;
            if ((unsigned)cxx < 32u && (unsigned)cyy < 8u && (unsigned)czz < 4u) {
                float w = ((ox ? gx : wx0) * (oy ? gy : wy0)) * (oz ? gz : wz0);
                atomicAdd(&brick[(czz * 8 + cyy) * 32 + cxx], q.w * w);
            }
        }
    }
    __syncthreads();

    *reinterpret_cast<float4*>(grid + o) =
        *reinterpret_cast<const float4*>(&brick[(cz * 8 + cy) * 32 + vx4 * 4]);
}

// ------------------------- separable 7-tap gaussian blur (pencil) ------------------
__global__ __launch_bounds__(256) void k_blur(const float* __restrict__ in,
                                              float* __restrict__ out, int shift)
{
    const long i = (long)blockIdx.x * 256 + threadIdx.x;
    const int p = (int)((i >> shift) & (DD - 1));

    const double e1 = 0.6065306597126334, e2 = 0.1353352832366127, e3 = 0.011108996538242306;
    const double s = 1.0 + 2.0 * (e1 + e2 + e3);
    const float kw[7] = {(float)(e3 / s), (float)(e2 / s), (float)(e1 / s), (float)(1.0 / s),
                         (float)(e1 / s), (float)(e2 / s), (float)(e3 / s)};

    float acc = 0.f;
    #pragma unroll
    for (int j = -3; j <= 3; ++j) {
        int q = p + j;
        if (q >= 0 && q < DD)
            acc = fmaf(kw[j + 3], in[i + ((long)j << shift)], acc);
    }
    out[i] = acc;
}

// ------------------ fused y+x blur: 32-row y-strips per (batch, z) -----------------
__global__ __launch_bounds__(256) void k_blur_yx(const float* __restrict__ in,
                                                 float* __restrict__ out)
{
    __shared__ float sin_[38 * 128];   // 19 KB: 32 rows + 3 halo each side
    __shared__ float sy[32 * 128];     // 16 KB: y-blur result

    const double e1 = 0.6065306597126334, e2 = 0.1353352832366127, e3 = 0.011108996538242306;
    const double ss = 1.0 + 2.0 * (e1 + e2 + e3);
    const float kw[7] = {(float)(e3 / ss), (float)(e2 / ss), (float)(e1 / ss), (float)(1.0 / ss),
                         (float)(e1 / ss), (float)(e2 / ss), (float)(e3 / ss)};

    const int tid = threadIdx.x;
    const int bid = blockIdx.x;            // [batch][z][ytile]
    const int ytile = bid & 3;
    const int z = (bid >> 2) & 127;
    const int batch = bid >> 9;
    const int y0 = ytile << 5;
    const size_t slab = (size_t)batch * D3 + (size_t)z * (DD * DD);

    for (int i = tid; i < 38 * 128; i += 256) {
        int row = i >> 7, xx = i & 127;
        int gy = y0 + row - 3;
        sin_[i] = (gy >= 0 && gy < DD) ? in[slab + (size_t)gy * DD + xx] : 0.f;
    }
    __syncthreads();

    for (int i = tid; i < 32 * 128; i += 256) {
        int r = i >> 7, xx = i & 127;
        float acc = 0.f;
        #pragma unroll
        for (int j = 0; j < 7; ++j)
            acc = fmaf(kw[j], sin_[(r + j) * 128 + xx], acc);
        sy[i] = acc;
    }
    __syncthreads();

    for (int i = tid; i < 32 * 128; i += 256) {
        int r = i >> 7, xx = i & 127;
        float acc = 0.f;
        #pragma unroll
        for (int j = -3; j <= 3; ++j) {
            int qx = xx + j;
            if (qx >= 0 && qx < DD)
                acc = fmaf(kw[j + 3], sy[r * 128 + qx], acc);
        }
        out[slab + (size_t)(y0 + r) * DD + xx] = acc;
    }
}

extern "C" void kernel_launch(void* const* d_in, const int* in_sizes, int n_in,
                              void* d_out, int out_size, void* d_ws, size_t ws_size,
                              hipStream_t stream) {
    const float* x   = (const float*)d_in[0];
    const float* w0  = (const float*)d_in[1];
    const float* b0  = (const float*)d_in[2];
    const float* w1  = (const float*)d_in[3];
    const float* b1  = (const float*)d_in[4];
    const float* w2  = (const float*)d_in[5];
    const float* b2  = (const float*)d_in[6];
    const float* w3  = (const float*)d_in[7];
    const float* b3  = (const float*)d_in[8];
    const float* w4  = (const float*)d_in[9];
    const float* b4  = (const float*)d_in[10];
    const float* wc  = (const float*)d_in[11];
    const float* bc  = (const float*)d_in[12];
    const float* wv  = (const float*)d_in[13];
    const float* bv  = (const float*)d_in[14];
    const float* c0  = (const float*)d_in[15];
    const float* v0  = (const float*)d_in[16];

    float* out = (float*)d_out;
    // d_out staging (consumed before k_binsplat rewrites d_out as the raw grid):
    float4* posval = (float4*)d_out;                  // [NB][NV] float4 = 8 MiB
    float* h4 = out + 4 * 1024 * 1024;                // 2048 f32 at +16 MiB
    // ws staging (consumed before blur-z rewrites ws with the 64MB grid):
    float4* sorted = (float4*)d_ws;                   // ~6 MiB actual (260K pts x ~1.45)
    unsigned* binCount  = (unsigned*)((char*)d_ws + (48u << 20));
    unsigned* binStart  = binCount + NBIN_TOT;        // NBIN_TOT+1 entries
    unsigned* binCursor = binStart + NBIN_TOT + 1;

    hipMemsetAsync(binCount, 0, NBIN_TOT * sizeof(unsigned), stream);

    k_mlp<<<1, 1024, 0, stream>>>(x, w0, b0, w1, b1, w2, b2, w3, b3, w4, b4, h4);

    k_heads<<<NV / 64, 256, 0, stream>>>(h4, wc, bc, wv, bv, c0, v0, posval);

    k_count<<<256, 256, 0, stream>>>(posval, binCount);
    k_scan<<<1, 1024, 0, stream>>>(binCount, binStart, binCursor);
    k_scatter<<<256, 256, 0, stream>>>(posval, binCursor, sorted);
    k_binsplat<<<NBIN_TOT, 256, 0, stream>>>(sorted, binStart, out);   // raw grid -> d_out

    const int nblk = (NB * D3) / 256;   // 65536
    k_blur<<<nblk, 256, 0, stream>>>(out, (float*)d_ws, 14);           // z: d_out -> ws
    k_blur_yx<<<NB * 512, 256, 0, stream>>>((float*)d_ws, out);        // y+x: ws -> d_out
}

// Round 6
// 355.735 us; speedup vs baseline: 2.0755x; 1.1446x over previous
//
#include <hip/hip_runtime.h>
#include <hip/hip_bf16.h>

#define DD 128
#define D3 (DD*DD*DD)      // 2097152
#define NB 8               // batch
#define NV 65536           // points
#define HID 256
#define LAT 128

// bricks: 32x8x4 voxels -> 4 x 16 x 32 = 2048 per batch, 16384 total
#define NBIN 2048
#define NBIN_TOT (NBIN*NB) // 16384

// round-to-nearest-even f32 -> bf16, returned as the (exactly representable) f32 value
__device__ __forceinline__ float rbf(float x) {
    unsigned u = __float_as_uint(x);
    unsigned r = (u + 0x7fffu + ((u >> 16) & 1u)) & 0xFFFF0000u;
    return __uint_as_float(r);
}

// ---------------- SIREN layer: one kernel per layer, 4 blocks x 256 threads --------
// block = 64 columns x 4 k-slices; SAME accumulation order as the monolithic k_mlp:
// sequential within slice, (p0+p1)+(p2+p3) across slices, identical rbf points.
// MODE 0: out = rbf(sin(rbf(30*rbf(rbf(s)+b))))          (first layer, K=128)
// MODE 1: out = rbf(sin(rbf(in + rbf(rbf(s)+b))))        (residual layers)
// MODE 2: out = rbf(rbf(s)+b)                            (final linear)
template<int K, int MODE>
__global__ __launch_bounds__(256) void k_layer(
    const float* __restrict__ in, const float* __restrict__ w,
    const float* __restrict__ bias, float* __restrict__ outp)
{
    __shared__ float in_s[NB * K];        // rbf is identity on already-bf16 values
    __shared__ float part[4 * 64 * 8];    // 8 KB
    const int tid = threadIdx.x;
    for (int i = tid; i < NB * K; i += 256) in_s[i] = rbf(in[i]);
    __syncthreads();

    const int cl = tid & 63;             // column within block (wave-contiguous)
    const int ks = tid >> 6;             // k-slice 0..3 (wave-uniform)
    const int col = blockIdx.x * 64 + cl;

    float acc[NB];
    #pragma unroll
    for (int b = 0; b < NB; ++b) acc[b] = 0.f;

    const int k0 = ks * (K / 4);
    #pragma unroll 8
    for (int k = k0; k < k0 + K / 4; ++k) {
        float wk = rbf(w[k * HID + col]);          // 256B/wave coalesced
        #pragma unroll
        for (int b = 0; b < NB; ++b) acc[b] = fmaf(in_s[b * K + k], wk, acc[b]);
    }

    float* pp = part + (ks * 64 + cl) * 8;
    #pragma unroll
    for (int b = 0; b < NB; ++b) pp[b] = acc[b];
    __syncthreads();

    #pragma unroll
    for (int u = 0; u < 2; ++u) {
        const int idx = tid * 2 + u;               // 512 outputs per block
        const int c2 = idx >> 3, b = idx & 7;
        const int gcol = blockIdx.x * 64 + c2;
        float s = (part[(0 * 64 + c2) * 8 + b] + part[(1 * 64 + c2) * 8 + b])
                + (part[(2 * 64 + c2) * 8 + b] + part[(3 * 64 + c2) * 8 + b]);
        float t = rbf(s);
        t = rbf(t + rbf(bias[gcol]));
        if (MODE == 0) {
            t = rbf(30.0f * t);
            t = rbf(sinf(t));
        } else if (MODE == 1) {
            float r = rbf(in_s[b * K + gcol] + t);
            t = rbf(sinf(r));
        }
        outp[b * HID + gcol] = t;
    }
}

// ----------------- heads: posval[b][v] = (px,py,pz,val), fully coalesced -----------
// block = 64 points x 4 k-slices (wave-uniform slice); tid = ks*64 + vl
#define PSTRIDE 17
__global__ __launch_bounds__(256) void k_heads(
    const float* __restrict__ h4,
    const float* __restrict__ wc, const float* __restrict__ bc,
    const float* __restrict__ wv, const float* __restrict__ bv,
    const float* __restrict__ coords0, const float* __restrict__ values0,
    float4* __restrict__ posval)
{
    __shared__ float hsT[HID * NB];              // [k][b], 8 KB, broadcast reads
    __shared__ float part[4 * 64 * PSTRIDE];     // 17.4 KB
    const int tid = threadIdx.x;
    for (int i = tid; i < NB * HID; i += 256) {
        int b = i >> 8, k = i & 255;
        hsT[k * 8 + b] = h4[b * HID + k];
    }
    __syncthreads();

    const int vl = tid & 63;          // point-in-block, contiguous per wave
    const int ks = tid >> 6;          // k-slice 0..3 (wave-uniform)
    const int v  = blockIdx.x * 64 + vl;

    float ac0[NB], ac1[NB], ac2[NB], av[NB];
    #pragma unroll
    for (int b = 0; b < NB; ++b) { ac0[b] = 0.f; ac1[b] = 0.f; ac2[b] = 0.f; av[b] = 0.f; }

    const float* pc = wc + (size_t)(ks * 64) * (3 * NV) + 3 * v;
    const float* pv = wv + (size_t)(ks * 64) * NV + v;
    const float* ph = hsT + (ks * 64) * 8;

    #pragma unroll 4
    for (int i = 0; i < 64; ++i) {
        float c0 = pc[0], c1 = pc[1], c2 = pc[2];   // contiguous 768B/wave
        float vv = pv[0];                            // contiguous 256B/wave
        float4 h03 = *reinterpret_cast<const float4*>(ph);      // LDS broadcast
        float4 h47 = *reinterpret_cast<const float4*>(ph + 4);
        ac0[0] = fmaf(h03.x, c0, ac0[0]); ac1[0] = fmaf(h03.x, c1, ac1[0]); ac2[0] = fmaf(h03.x, c2, ac2[0]); av[0] = fmaf(h03.x, vv, av[0]);
        ac0[1] = fmaf(h03.y, c0, ac0[1]); ac1[1] = fmaf(h03.y, c1, ac1[1]); ac2[1] = fmaf(h03.y, c2, ac2[1]); av[1] = fmaf(h03.y, vv, av[1]);
        ac0[2] = fmaf(h03.z, c0, ac0[2]); ac1[2] = fmaf(h03.z, c1, ac1[2]); ac2[2] = fmaf(h03.z, c2, ac2[2]); av[2] = fmaf(h03.z, vv, av[2]);
        ac0[3] = fmaf(h03.w, c0, ac0[3]); ac1[3] = fmaf(h03.w, c1, ac1[3]); ac2[3] = fmaf(h03.w, c2, ac2[3]); av[3] = fmaf(h03.w, vv, av[3]);
        ac0[4] = fmaf(h47.x, c0, ac0[4]); ac1[4] = fmaf(h47.x, c1, ac1[4]); ac2[4] = fmaf(h47.x, c2, ac2[4]); av[4] = fmaf(h47.x, vv, av[4]);
        ac0[5] = fmaf(h47.y, c0, ac0[5]); ac1[5] = fmaf(h47.y, c1, ac1[5]); ac2[5] = fmaf(h47.y, c2, ac2[5]); av[5] = fmaf(h47.y, vv, av[5]);
        ac0[6] = fmaf(h47.z, c0, ac0[6]); ac1[6] = fmaf(h47.z, c1, ac1[6]); ac2[6] = fmaf(h47.z, c2, ac2[6]); av[6] = fmaf(h47.z, vv, av[6]);
        ac0[7] = fmaf(h47.w, c0, ac0[7]); ac1[7] = fmaf(h47.w, c1, ac1[7]); ac2[7] = fmaf(h47.w, c2, ac2[7]); av[7] = fmaf(h47.w, vv, av[7]);
        pc += (size_t)3 * NV;
        pv += NV;
        ph += 8;
    }

    const float factor = 0.5f * DD;
    const int bp = tid >> 6;           // reduction: thread handles batch bp (+phase*4)
    float* pp = part + (ks * 64 + vl) * PSTRIDE;

    #pragma unroll
    for (int phase = 0; phase < 2; ++phase) {
        if (phase) __syncthreads();
        #pragma unroll
        for (int q = 0; q < 4; ++q) {
            int b = phase * 4 + q;
            pp[q * 4 + 0] = ac0[b]; pp[q * 4 + 1] = ac1[b];
            pp[q * 4 + 2] = ac2[b]; pp[q * 4 + 3] = av[b];
        }
        __syncthreads();
        {
            const int b = phase * 4 + bp;
            float A0 = 0.f, A1 = 0.f, A2 = 0.f, A3 = 0.f;
            #pragma unroll
            for (int k2 = 0; k2 < 4; ++k2) {
                const float* rp = part + (k2 * 64 + vl) * PSTRIDE + bp * 4;
                A0 += rp[0]; A1 += rp[1]; A2 += rp[2]; A3 += rp[3];
            }
            float px = factor * (coords0[3 * v]     + (A0 + bc[3 * v]))     + factor;
            float py = factor * (coords0[3 * v + 1] + (A1 + bc[3 * v + 1])) + factor;
            float pz = factor * (coords0[3 * v + 2] + (A2 + bc[3 * v + 2])) + factor;
            float val = fmaxf(values0[v] + (A3 + bv[v]), 0.f);
            posval[(size_t)b * NV + v] = make_float4(px, py, pz, val);
        }
    }
}

// ----------------------------- binning helpers -------------------------------------
// brick(bx,by,bz) covers voxels x:[bx*32,+32) y:[by*8,+8) z:[bz*4,+4); bin=(bz*16+by)*4+bx
__device__ __forceinline__ bool point_base(float4 q, int& ix, int& iy, int& iz) {
    if (q.w == 0.f) return false;                   // relu-zeroed: no contribution
    ix = (int)floorf(q.x); iy = (int)floorf(q.y); iz = (int)floorf(q.z);
    return ix >= -1 && ix <= 127 && iy >= -1 && iy <= 127 && iz >= -1 && iz <= 127;
}

__device__ __forceinline__ void brick_span(int ix, int iy, int iz,
                                           int& bx0, int& bx1, int& by0, int& by1,
                                           int& bz0, int& bz1) {
    bx0 = (ix < 0 ? 0 : ix) >> 5;  bx1 = (ix + 1 > 127 ? 127 : ix + 1) >> 5;
    by0 = (iy < 0 ? 0 : iy) >> 3;  by1 = (iy + 1 > 127 ? 127 : iy + 1) >> 3;
    bz0 = (iz < 0 ? 0 : iz) >> 2;  bz1 = (iz + 1 > 127 ? 127 : iz + 1) >> 2;
}

// --------------- k_count: LDS histogram of (duplicated) entries per brick ----------
__global__ __launch_bounds__(256) void k_count(const float4* __restrict__ posval,
                                               unsigned* __restrict__ binCount)
{
    __shared__ unsigned hist[NBIN];   // 8 KB
    const int tid = threadIdx.x;
    const int batch = blockIdx.x >> 5;
    const size_t base = (size_t)batch * NV + (blockIdx.x & 31) * 2048;
    for (int i = tid; i < NBIN; i += 256) hist[i] = 0;
    __syncthreads();
    #pragma unroll
    for (int j = 0; j < 8; ++j) {
        float4 q = posval[base + j * 256 + tid];
        int ix, iy, iz;
        if (point_base(q, ix, iy, iz)) {
            int bx0, bx1, by0, by1, bz0, bz1;
            brick_span(ix, iy, iz, bx0, bx1, by0, by1, bz0, bz1);
            for (int bz = bz0; bz <= bz1; ++bz)
                for (int by = by0; by <= by1; ++by)
                    for (int bx = bx0; bx <= bx1; ++bx)
                        atomicAdd(&hist[(bz * 16 + by) * 4 + bx], 1u);
        }
    }
    __syncthreads();
    for (int i = tid; i < NBIN; i += 256) {
        unsigned c = hist[i];
        if (c) atomicAdd(&binCount[batch * NBIN + i], c);
    }
}

// --------------- k_scan: exclusive scan over 16384 bins (single block) -------------
__global__ __launch_bounds__(1024) void k_scan(const unsigned* __restrict__ cnt,
                                               unsigned* __restrict__ start,
                                               unsigned* __restrict__ cursor)
{
    __shared__ unsigned partial[1024];
    const int t = threadIdx.x;
    const int base = t * 16;
    unsigned s = 0;
    #pragma unroll
    for (int j = 0; j < 16; ++j) s += cnt[base + j];
    partial[t] = s;
    __syncthreads();
    for (int off = 1; off < 1024; off <<= 1) {
        unsigned mine = partial[t];
        unsigned add = (t >= off) ? partial[t - off] : 0u;
        __syncthreads();
        partial[t] = mine + add;
        __syncthreads();
    }
    unsigned run = (t > 0) ? partial[t - 1] : 0u;
    #pragma unroll
    for (int j = 0; j < 16; ++j) {
        start[base + j] = run;
        cursor[base + j] = run;
        run += cnt[base + j];
    }
    if (t == 1023) start[NBIN_TOT] = partial[1023];
}

// -------- k_scatter: copy each point into every touched brick's contiguous range ----
__global__ __launch_bounds__(256) void k_scatter(const float4* __restrict__ posval,
                                                 unsigned* __restrict__ binCursor,
                                                 float4* __restrict__ sorted)
{
    __shared__ unsigned hist[NBIN];    // counts, then reused as local cursor
    __shared__ unsigned bbase[NBIN];
    const int tid = threadIdx.x;
    const int batch = blockIdx.x >> 5;
    const size_t base = (size_t)batch * NV + (blockIdx.x & 31) * 2048;
    for (int i = tid; i < NBIN; i += 256) hist[i] = 0;
    __syncthreads();

    float4 q[8];
    #pragma unroll
    for (int j = 0; j < 8; ++j) {
        q[j] = posval[base + j * 256 + tid];
        int ix, iy, iz;
        if (point_base(q[j], ix, iy, iz)) {
            int bx0, bx1, by0, by1, bz0, bz1;
            brick_span(ix, iy, iz, bx0, bx1, by0, by1, bz0, bz1);
            for (int bz = bz0; bz <= bz1; ++bz)
                for (int by = by0; by <= by1; ++by)
                    for (int bx = bx0; bx <= bx1; ++bx)
                        atomicAdd(&hist[(bz * 16 + by) * 4 + bx], 1u);
        }
    }
    __syncthreads();
    for (int i = tid; i < NBIN; i += 256) {
        unsigned c = hist[i];
        bbase[i] = c ? atomicAdd(&binCursor[batch * NBIN + i], c) : 0u;
    }
    __syncthreads();
    for (int i = tid; i < NBIN; i += 256) hist[i] = 0;   // reuse as local cursor
    __syncthreads();
    #pragma unroll
    for (int j = 0; j < 8; ++j) {
        int ix, iy, iz;
        if (point_base(q[j], ix, iy, iz)) {
            int bx0, bx1, by0, by1, bz0, bz1;
            brick_span(ix, iy, iz, bx0, bx1, by0, by1, bz0, bz1);
            for (int bz = bz0; bz <= bz1; ++bz)
                for (int by = by0; by <= by1; ++by)
                    for (int bx = bx0; bx <= bx1; ++bx) {
                        int bin = (bz * 16 + by) * 4 + bx;
                        unsigned r = atomicAdd(&hist[bin], 1u);
                        sorted[bbase[bin] + r] = q[j];
                    }
        }
    }
}

// -------- k_binsplat: one block per 32x8x4 brick; exact list; LDS accumulate -------
__global__ __launch_bounds__(256) void k_binsplat(const float4* __restrict__ sorted,
                                                  const unsigned* __restrict__ binStart,
                                                  float* __restrict__ grid)
{
    __shared__ float brick[4 * 8 * 32];   // 4 KB
    const int tid = threadIdx.x;
    const int bid = blockIdx.x;           // [batch][bz 0..31][by 0..15][bx 0..3]
    const int bx = bid & 3;
    const int by = (bid >> 2) & 15;
    const int bz = (bid >> 6) & 31;
    const int batch = bid >> 11;
    const int x0 = bx << 5, y0 = by << 3, z0 = bz << 2;

    const unsigned s = binStart[bid], e = binStart[bid + 1];

    const int vx4 = tid & 7, cy = (tid >> 3) & 7, cz = tid >> 6;
    const size_t o = (size_t)batch * D3 + (size_t)(z0 + cz) * (DD * DD)
                   + (size_t)(y0 + cy) * DD + x0 + vx4 * 4;

    if (s == e) {   // empty brick: pure zero-write (replaces global memset)
        *reinterpret_cast<float4*>(grid + o) = make_float4(0.f, 0.f, 0.f, 0.f);
        return;
    }

    for (int i = tid; i < 1024; i += 256) brick[i] = 0.f;
    __syncthreads();

    for (unsigned i = s + tid; i < e; i += 256) {
        float4 q = sorted[i];
        float fx = floorf(q.x), fy = floorf(q.y), fz = floorf(q.z);
        int vx = (int)fx - x0, vy = (int)fy - y0, vz = (int)fz - z0;
        float gx = q.x - fx, gy = q.y - fy, gz = q.z - fz;
        float wx0 = 1.f - gx, wy0 = 1.f - gy, wz0 = 1.f - gz;
        #pragma unroll
        for (int oz = 0; oz < 2; ++oz)
        #pragma unroll
        for (int oy = 0; oy < 2; ++oy)
        #pragma unroll
        for (int ox = 0; ox < 2; ++ox) {
            int cxx = vx + ox, cyy = vy + oy, czz = vz + oz;
            if ((unsigned)cxx < 32u && (unsigned)cyy < 8u && (unsigned)czz < 4u) {
                float w = ((ox ? gx : wx0) * (oy ? gy : wy0)) * (oz ? gz : wz0);
                atomicAdd(&brick[(czz * 8 + cyy) * 32 + cxx], q.w * w);
            }
        }
    }
    __syncthreads();

    *reinterpret_cast<float4*>(grid + o) =
        *reinterpret_cast<const float4*>(&brick[(cz * 8 + cy) * 32 + vx4 * 4]);
}

// ------------------------- separable 7-tap gaussian blur (pencil) ------------------
__global__ __launch_bounds__(256) void k_blur(const float* __restrict__ in,
                                              float* __restrict__ out, int shift)
{
    const long i = (long)blockIdx.x * 256 + threadIdx.x;
    const int p = (int)((i >> shift) & (DD - 1));

    const double e1 = 0.6065306597126334, e2 = 0.1353352832366127, e3 = 0.011108996538242306;
    const double s = 1.0 + 2.0 * (e1 + e2 + e3);
    const float kw[7] = {(float)(e3 / s), (float)(e2 / s), (float)(e1 / s), (float)(1.0 / s),
                         (float)(e1 / s), (float)(e2 / s), (float)(e3 / s)};

    float acc = 0.f;
    #pragma unroll
    for (int j = -3; j <= 3; ++j) {
        int q = p + j;
        if (q >= 0 && q < DD)
            acc = fmaf(kw[j + 3], in[i + ((long)j << shift)], acc);
    }
    out[i] = acc;
}

// ------------------ fused y+x blur: 32-row y-strips per (batch, z) -----------------
__global__ __launch_bounds__(256) void k_blur_yx(const float* __restrict__ in,
                                                 float* __restrict__ out)
{
    __shared__ float sin_[38 * 128];   // 19 KB: 32 rows + 3 halo each side
    __shared__ float sy[32 * 128];     // 16 KB: y-blur result

    const double e1 = 0.6065306597126334, e2 = 0.1353352832366127, e3 = 0.011108996538242306;
    const double ss = 1.0 + 2.0 * (e1 + e2 + e3);
    const float kw[7] = {(float)(e3 / ss), (float)(e2 / ss), (float)(e1 / ss), (float)(1.0 / ss),
                         (float)(e1 / ss), (float)(e2 / ss), (float)(e3 / ss)};

    const int tid = threadIdx.x;
    const int bid = blockIdx.x;            // [batch][z][ytile]
    const int ytile = bid & 3;
    const int z = (bid >> 2) & 127;
    const int batch = bid >> 9;
    const int y0 = ytile << 5;
    const size_t slab = (size_t)batch * D3 + (size_t)z * (DD * DD);

    for (int i = tid; i < 38 * 128; i += 256) {
        int row = i >> 7, xx = i & 127;
        int gy = y0 + row - 3;
        sin_[i] = (gy >= 0 && gy < DD) ? in[slab + (size_t)gy * DD + xx] : 0.f;
    }
    __syncthreads();

    for (int i = tid; i < 32 * 128; i += 256) {
        int r = i >> 7, xx = i & 127;
        float acc = 0.f;
        #pragma unroll
        for (int j = 0; j < 7; ++j)
            acc = fmaf(kw[j], sin_[(r + j) * 128 + xx], acc);
        sy[i] = acc;
    }
    __syncthreads();

    for (int i = tid; i < 32 * 128; i += 256) {
        int r = i >> 7, xx = i & 127;
        float acc = 0.f;
        #pragma unroll
        for (int j = -3; j <= 3; ++j) {
            int qx = xx + j;
            if (qx >= 0 && qx < DD)
                acc = fmaf(kw[j + 3], sy[r * 128 + qx], acc);
        }
        out[slab + (size_t)(y0 + r) * DD + xx] = acc;
    }
}

extern "C" void kernel_launch(void* const* d_in, const int* in_sizes, int n_in,
                              void* d_out, int out_size, void* d_ws, size_t ws_size,
                              hipStream_t stream) {
    const float* x   = (const float*)d_in[0];
    const float* w0  = (const float*)d_in[1];
    const float* b0  = (const float*)d_in[2];
    const float* w1  = (const float*)d_in[3];
    const float* b1  = (const float*)d_in[4];
    const float* w2  = (const float*)d_in[5];
    const float* b2  = (const float*)d_in[6];
    const float* w3  = (const float*)d_in[7];
    const float* b3  = (const float*)d_in[8];
    const float* w4  = (const float*)d_in[9];
    const float* b4  = (const float*)d_in[10];
    const float* wc  = (const float*)d_in[11];
    const float* bc  = (const float*)d_in[12];
    const float* wv  = (const float*)d_in[13];
    const float* bv  = (const float*)d_in[14];
    const float* c0  = (const float*)d_in[15];
    const float* v0  = (const float*)d_in[16];

    float* out = (float*)d_out;
    // d_out staging (consumed before k_binsplat rewrites d_out as the raw grid):
    float4* posval = (float4*)d_out;                  // [NB][NV] float4 = 8 MiB
    float* h4 = out + 4 * 1024 * 1024;                // at +16 MiB
    float* hA = h4 + 2048;
    float* hB = hA + 2048;
    // ws staging (consumed before blur-z rewrites ws with the 64MB grid):
    float4* sorted = (float4*)d_ws;                   // ~6 MiB actual
    unsigned* binCount  = (unsigned*)((char*)d_ws + (48u << 20));
    unsigned* binStart  = binCount + NBIN_TOT;        // NBIN_TOT+1 entries
    unsigned* binCursor = binStart + NBIN_TOT + 1;

    hipMemsetAsync(binCount, 0, NBIN_TOT * sizeof(unsigned), stream);

    // SIREN MLP: 5 per-layer kernels, 4 blocks each (weight fetch spread over 4 CUs)
    k_layer<LAT, 0><<<4, 256, 0, stream>>>(x,  w0, b0, hA);
    k_layer<HID, 1><<<4, 256, 0, stream>>>(hA, w1, b1, hB);
    k_layer<HID, 1><<<4, 256, 0, stream>>>(hB, w2, b2, hA);
    k_layer<HID, 1><<<4, 256, 0, stream>>>(hA, w3, b3, hB);
    k_layer<HID, 2><<<4, 256, 0, stream>>>(hB, w4, b4, h4);

    k_heads<<<NV / 64, 256, 0, stream>>>(h4, wc, bc, wv, bv, c0, v0, posval);

    k_count<<<256, 256, 0, stream>>>(posval, binCount);
    k_scan<<<1, 1024, 0, stream>>>(binCount, binStart, binCursor);
    k_scatter<<<256, 256, 0, stream>>>(posval, binCursor, sorted);
    k_binsplat<<<NBIN_TOT, 256, 0, stream>>>(sorted, binStart, out);   // raw grid -> d_out

    const int nblk = (NB * D3) / 256;   // 65536
    k_blur<<<nblk, 256, 0, stream>>>(out, (float*)d_ws, 14);           // z: d_out -> ws
    k_blur_yx<<<NB * 512, 256, 0, stream>>>((float*)d_ws, out);        // y+x: ws -> d_out
}